// Round 1
// baseline (837.839 us; speedup 1.0000x reference)
//
#include <hip/hip_runtime.h>
#include <math.h>

#define BB 4
#define CC 256
#define HH 128
#define WW 128
#define NN (HH*WW)
#define DD 32

// ---------------------------------------------------------------------------
// K1: QKV projection.  Q/K/V[b][d][n] = sum_c x[b][c][n]*w[d][c] + bias[d]
// grid (N/64, B), block 256 = (64 lanes n) x (4 d-groups of 8)
// ---------------------------------------------------------------------------
__global__ __launch_bounds__(256) void qkv_kernel(
    const float* __restrict__ x,
    const float* __restrict__ wq, const float* __restrict__ bq,
    const float* __restrict__ wk, const float* __restrict__ bk,
    const float* __restrict__ wv, const float* __restrict__ bv,
    float* __restrict__ Q, float* __restrict__ K, float* __restrict__ V)
{
    __shared__ float xs[CC][64];                       // 64 KB
    const int b  = blockIdx.y;
    const int n0 = blockIdx.x * 64;
    const float* xb = x + (size_t)b * CC * NN;
    for (int i = threadIdx.x; i < CC * 64; i += 256) { // coalesced 256B/wave
        int c = i >> 6, j = i & 63;
        xs[c][j] = xb[(size_t)c * NN + n0 + j];
    }
    __syncthreads();
    const int j  = threadIdx.x & 63;
    const int dg = threadIdx.x >> 6;                   // wave-uniform (wave=64)
    float aq[8] = {0,0,0,0,0,0,0,0};
    float ak[8] = {0,0,0,0,0,0,0,0};
    float av[8] = {0,0,0,0,0,0,0,0};
    for (int c = 0; c < CC; c += 4) {
        float x0 = xs[c][j], x1 = xs[c+1][j], x2 = xs[c+2][j], x3 = xs[c+3][j];
        #pragma unroll
        for (int dd = 0; dd < 8; ++dd) {
            int d = dg * 8 + dd;
            float4 w;
            w = *(const float4*)(wq + d * CC + c);
            aq[dd] += w.x*x0 + w.y*x1 + w.z*x2 + w.w*x3;
            w = *(const float4*)(wk + d * CC + c);
            ak[dd] += w.x*x0 + w.y*x1 + w.z*x2 + w.w*x3;
            w = *(const float4*)(wv + d * CC + c);
            av[dd] += w.x*x0 + w.y*x1 + w.z*x2 + w.w*x3;
        }
    }
    #pragma unroll
    for (int dd = 0; dd < 8; ++dd) {
        int d = dg * 8 + dd;
        size_t o = ((size_t)b * DD + d) * NN + n0 + j;
        Q[o] = aq[dd] + bq[d];
        K[o] = ak[dd] + bk[d];
        V[o] = av[dd] + bv[d];
    }
}

// ---------------------------------------------------------------------------
// K2: partial energy.  Ep[s][b][d][e] = sum_{n in chunk s} Q[b][d][n]K[b][e][n]
// grid (64, B), block 256 = 16x16 groups, 2x2 register tile.
// LDS rows padded to 130 -> bank = (2*row + n) & 31 -> <=2-way (free).
// ---------------------------------------------------------------------------
__global__ __launch_bounds__(256) void energy_kernel(
    const float* __restrict__ Q, const float* __restrict__ K,
    float* __restrict__ Ep)
{
    __shared__ float Qs[DD][130];
    __shared__ float Ks[DD][130];
    const int b  = blockIdx.y;
    const int s  = blockIdx.x;            // 0..63
    const int n0 = s * 256;
    const int d0 = (threadIdx.x >> 4) * 2;
    const int e0 = (threadIdx.x & 15) * 2;
    float a00 = 0.f, a01 = 0.f, a10 = 0.f, a11 = 0.f;
    for (int sc = 0; sc < 2; ++sc) {
        __syncthreads();
        for (int i = threadIdx.x; i < DD * 128; i += 256) {
            int r = i >> 7, cc = i & 127;
            size_t g = ((size_t)b * DD + r) * NN + n0 + sc * 128 + cc;
            Qs[r][cc] = Q[g];
            Ks[r][cc] = K[g];
        }
        __syncthreads();
        for (int nn = 0; nn < 128; ++nn) {
            float q0 = Qs[d0][nn], q1 = Qs[d0+1][nn];
            float k0 = Ks[e0][nn], k1 = Ks[e0+1][nn];
            a00 += q0*k0; a01 += q0*k1; a10 += q1*k0; a11 += q1*k1;
        }
    }
    float* o = Ep + ((size_t)s * BB + b) * (DD * DD);
    o[d0*DD + e0]       = a00;
    o[d0*DD + e0 + 1]   = a01;
    o[(d0+1)*DD + e0]   = a10;
    o[(d0+1)*DD + e0+1] = a11;
}

// ---------------------------------------------------------------------------
// K3: reduce partials + softmax.  softmax(rowmax-E) == softmax(-E).
// grid B, block (32 e, 32 d).  Stores attention TRANSPOSED: attT[b][e][d].
// ---------------------------------------------------------------------------
__global__ __launch_bounds__(1024) void softmax_kernel(
    const float* __restrict__ Ep, float* __restrict__ attT)
{
    const int b = blockIdx.x;
    const int e = threadIdx.x, d = threadIdx.y;
    float s = 0.f;
    for (int p = 0; p < 64; ++p)
        s += Ep[((size_t)p * BB + b) * (DD * DD) + d * DD + e];
    float nv = -s;
    float m = nv;
    for (int off = 16; off > 0; off >>= 1) m = fmaxf(m, __shfl_xor(m, off, 32));
    float pe = expf(nv - m);
    float su = pe;
    for (int off = 16; off > 0; off >>= 1) su += __shfl_xor(su, off, 32);
    attT[(size_t)b * (DD * DD) + e * DD + d] = pe / su;
}

// ---------------------------------------------------------------------------
// K4: PV.  AO[b][d][n] = sum_e att[d][e] * V[b][e][n]
// grid (N/256, B), block 256 (thread = one n, 32 d accumulators).
// ---------------------------------------------------------------------------
__global__ __launch_bounds__(256) void pv_kernel(
    const float* __restrict__ V, const float* __restrict__ attT,
    float* __restrict__ AO)
{
    __shared__ float Vs[DD][256];          // bank = n&31 per lane: conflict-free
    __shared__ float at4[DD][DD];          // attT[e][d]
    const int b  = blockIdx.y;
    const int n0 = blockIdx.x * 256;
    for (int i = threadIdx.x; i < DD * 256; i += 256) {
        int r = i >> 8, cc = i & 255;
        Vs[r][cc] = V[((size_t)b * DD + r) * NN + n0 + cc];
    }
    for (int i = threadIdx.x; i < DD * DD; i += 256)
        at4[i >> 5][i & 31] = attT[(size_t)b * (DD * DD) + i];
    __syncthreads();
    const int t = threadIdx.x;
    float acc[DD];
    #pragma unroll
    for (int d = 0; d < DD; ++d) acc[d] = 0.f;
    #pragma unroll 4
    for (int e = 0; e < DD; ++e) {
        float v = Vs[e][t];
        const float4* ar = (const float4*)at4[e];   // uniform -> broadcast
        #pragma unroll
        for (int dq = 0; dq < 8; ++dq) {
            float4 a = ar[dq];
            acc[4*dq+0] += a.x * v; acc[4*dq+1] += a.y * v;
            acc[4*dq+2] += a.z * v; acc[4*dq+3] += a.w * v;
        }
    }
    #pragma unroll
    for (int d = 0; d < DD; ++d)
        AO[((size_t)b * DD + d) * NN + n0 + t] = acc[d];
}

// ---------------------------------------------------------------------------
// K5: 3x3 conv (32->256) + exact GELU + gamma*out + x.
// grid (W/8, H/4, B), block 256 = (64 c_out lanes) x (4 tile rows).
// Thread owns c_out in {cg, cg+64, cg+128, cg+192} x 8 cols of its row.
// Patch reads are wave-uniform (LDS broadcast); stores lane-coalesced per d.
// ---------------------------------------------------------------------------
__global__ __launch_bounds__(256) void conv_kernel(
    const float* __restrict__ AO, const float* __restrict__ wp,
    const float* __restrict__ gammap, const float* __restrict__ x,
    float* __restrict__ out)
{
    __shared__ float ap[DD][6][12];        // 9.2 KB patch, zero-padded halo
    const int b  = blockIdx.z;
    const int r0 = blockIdx.y * 4;
    const int c0 = blockIdx.x * 8;
    for (int i = threadIdx.x; i < DD * 6 * 12; i += 256) {
        int ci = i / 72, rem = i % 72;
        int rr = rem / 12, cc = rem % 12;
        int h = r0 - 1 + rr, w = c0 - 1 + cc;
        float v = 0.f;
        if (cc < 10 && h >= 0 && h < HH && w >= 0 && w < WW)
            v = AO[((size_t)b * DD + ci) * NN + h * WW + w];
        ap[ci][rr][cc] = v;
    }
    __syncthreads();
    const int cg = threadIdx.x & 63;
    const int pg = threadIdx.x >> 6;       // tile row, wave-uniform
    float acc[4][8];
    #pragma unroll
    for (int k = 0; k < 4; ++k)
        #pragma unroll
        for (int p = 0; p < 8; ++p) acc[k][p] = 0.f;

    for (int ci = 0; ci < DD; ++ci) {
        float in0[10], in1[10], in2[10];
        #pragma unroll
        for (int cc = 0; cc < 10; ++cc) {
            in0[cc] = ap[ci][pg][cc];
            in1[cc] = ap[ci][pg + 1][cc];
            in2[cc] = ap[ci][pg + 2][cc];
        }
        #pragma unroll
        for (int k = 0; k < 4; ++k) {
            const float* wb = wp + ((size_t)(cg + 64 * k) * DD + ci) * 9;
            float w0=wb[0], w1=wb[1], w2=wb[2], w3=wb[3], w4=wb[4],
                  w5=wb[5], w6=wb[6], w7=wb[7], w8=wb[8];
            #pragma unroll
            for (int p = 0; p < 8; ++p) {
                acc[k][p] += w0*in0[p]   + w1*in0[p+1] + w2*in0[p+2]
                           + w3*in1[p]   + w4*in1[p+1] + w5*in1[p+2]
                           + w6*in2[p]   + w7*in2[p+1] + w8*in2[p+2];
            }
        }
    }
    const float g0 = gammap[0];
    const int hrow = r0 + pg;
    #pragma unroll
    for (int k = 0; k < 4; ++k) {
        int co = cg + 64 * k;
        size_t base = ((size_t)b * CC + co) * NN + (size_t)hrow * WW + c0;
        #pragma unroll
        for (int p = 0; p < 8; ++p) {
            float o  = acc[k][p];
            float ge = 0.5f * o * (1.0f + erff(o * 0.70710678118654752f));
            out[base + p] = g0 * ge + x[base + p];
        }
    }
}

// ---------------------------------------------------------------------------
extern "C" void kernel_launch(void* const* d_in, const int* in_sizes, int n_in,
                              void* d_out, int out_size, void* d_ws, size_t ws_size,
                              hipStream_t stream)
{
    const float* x  = (const float*)d_in[0];
    const float* wq = (const float*)d_in[1];
    const float* bq = (const float*)d_in[2];
    const float* wk = (const float*)d_in[3];
    const float* bk = (const float*)d_in[4];
    const float* wv = (const float*)d_in[5];
    const float* bv = (const float*)d_in[6];
    const float* wp = (const float*)d_in[7];
    const float* gm = (const float*)d_in[8];
    float* out = (float*)d_out;

    // Q/K/V scratch lives inside d_out (16.7M floats); conv overwrites all of
    // d_out after their last use.  ws only needs AO + energy buffers (~9.5 MB).
    float* Qb = out;
    float* Kb = out + (size_t)2097152;
    float* Vb = out + (size_t)4194304;
    float* ws  = (float*)d_ws;
    float* AO  = ws;                        // 2097152 floats
    float* Ep  = ws + (size_t)2097152;      // 262144 floats
    float* ATT = ws + (size_t)2359296;      // 4096 floats

    qkv_kernel   <<<dim3(NN/64, BB), 256, 0, stream>>>(x, wq, bq, wk, bk, wv, bv, Qb, Kb, Vb);
    energy_kernel<<<dim3(64, BB),    256, 0, stream>>>(Qb, Kb, Ep);
    softmax_kernel<<<dim3(BB), dim3(32, 32), 0, stream>>>(Ep, ATT);
    pv_kernel    <<<dim3(NN/256, BB), 256, 0, stream>>>(Vb, ATT, AO);
    conv_kernel  <<<dim3(WW/8, HH/4, BB), 256, 0, stream>>>(AO, wp, gm, x, out);
}

// Round 2
// 287.850 us; speedup vs baseline: 2.9107x; 2.9107x over previous
//
#include <hip/hip_runtime.h>
#include <hip/hip_bf16.h>
#include <math.h>

#define BB 4
#define CC 256
#define HH 128
#define WW 128
#define NN (HH*WW)
#define DD 32

// AOT: attention output, bf16, spatially padded +1 border, ci padded 32->40.
// Layout [b][130 rows][130 cols][40 ci]  (border rows/cols zeroed by memset)
#define AOT_CI   40
#define AOT_ROWE (130*AOT_CI)            // elems per padded row (5200)
#define AOT_IMGE (130*AOT_ROWE)          // elems per batch (676000)
#define AOT_BYTES ((size_t)BB*AOT_IMGE*2)      // 5,408,000
#define AOT_ALLOC (AOT_BYTES + 1024)           // slack for linear-copy overrun

#define WT_BYTES (9*256*AOT_CI*2)        // 184,320
#define LDS_PATCH 31744                  // 31 x 1024 (covers 3*130*80 = 31200)
#define A_SLAB    20480                  // 256*80

typedef __attribute__((ext_vector_type(8))) short bf16x8;
typedef __attribute__((ext_vector_type(4))) float f32x4;

__device__ inline void async_copy16(void* lds, const void* g) {
    __builtin_amdgcn_global_load_lds(
        (const __attribute__((address_space(1))) unsigned int*)g,
        (__attribute__((address_space(3))) unsigned int*)lds, 16, 0, 0);
}

__device__ inline unsigned short f2bf(float f) {
    __hip_bfloat16 h = __float2bfloat16(f);
    return *reinterpret_cast<unsigned short*>(&h);
}

// ---------------------------------------------------------------------------
// K1: QKV projection (unchanged from round 1 — passed).
// ---------------------------------------------------------------------------
__global__ __launch_bounds__(256) void qkv_kernel(
    const float* __restrict__ x,
    const float* __restrict__ wq, const float* __restrict__ bq,
    const float* __restrict__ wk, const float* __restrict__ bk,
    const float* __restrict__ wv, const float* __restrict__ bv,
    float* __restrict__ Q, float* __restrict__ K, float* __restrict__ V)
{
    __shared__ float xs[CC][64];
    const int b  = blockIdx.y;
    const int n0 = blockIdx.x * 64;
    const float* xb = x + (size_t)b * CC * NN;
    for (int i = threadIdx.x; i < CC * 64; i += 256) {
        int c = i >> 6, j = i & 63;
        xs[c][j] = xb[(size_t)c * NN + n0 + j];
    }
    __syncthreads();
    const int j  = threadIdx.x & 63;
    const int dg = threadIdx.x >> 6;
    float aq[8] = {0,0,0,0,0,0,0,0};
    float ak[8] = {0,0,0,0,0,0,0,0};
    float av[8] = {0,0,0,0,0,0,0,0};
    for (int c = 0; c < CC; c += 4) {
        float x0 = xs[c][j], x1 = xs[c+1][j], x2 = xs[c+2][j], x3 = xs[c+3][j];
        #pragma unroll
        for (int dd = 0; dd < 8; ++dd) {
            int d = dg * 8 + dd;
            float4 w;
            w = *(const float4*)(wq + d * CC + c);
            aq[dd] += w.x*x0 + w.y*x1 + w.z*x2 + w.w*x3;
            w = *(const float4*)(wk + d * CC + c);
            ak[dd] += w.x*x0 + w.y*x1 + w.z*x2 + w.w*x3;
            w = *(const float4*)(wv + d * CC + c);
            av[dd] += w.x*x0 + w.y*x1 + w.z*x2 + w.w*x3;
        }
    }
    #pragma unroll
    for (int dd = 0; dd < 8; ++dd) {
        int d = dg * 8 + dd;
        size_t o = ((size_t)b * DD + d) * NN + n0 + j;
        Q[o] = aq[dd] + bq[d];
        K[o] = ak[dd] + bk[d];
        V[o] = av[dd] + bv[d];
    }
}

// ---------------------------------------------------------------------------
// K2: partial energy (unchanged).
// ---------------------------------------------------------------------------
__global__ __launch_bounds__(256) void energy_kernel(
    const float* __restrict__ Q, const float* __restrict__ K,
    float* __restrict__ Ep)
{
    __shared__ float Qs[DD][130];
    __shared__ float Ks[DD][130];
    const int b  = blockIdx.y;
    const int s  = blockIdx.x;
    const int n0 = s * 256;
    const int d0 = (threadIdx.x >> 4) * 2;
    const int e0 = (threadIdx.x & 15) * 2;
    float a00 = 0.f, a01 = 0.f, a10 = 0.f, a11 = 0.f;
    for (int sc = 0; sc < 2; ++sc) {
        __syncthreads();
        for (int i = threadIdx.x; i < DD * 128; i += 256) {
            int r = i >> 7, cc = i & 127;
            size_t g = ((size_t)b * DD + r) * NN + n0 + sc * 128 + cc;
            Qs[r][cc] = Q[g];
            Ks[r][cc] = K[g];
        }
        __syncthreads();
        for (int nn = 0; nn < 128; ++nn) {
            float q0 = Qs[d0][nn], q1 = Qs[d0+1][nn];
            float k0 = Ks[e0][nn], k1 = Ks[e0+1][nn];
            a00 += q0*k0; a01 += q0*k1; a10 += q1*k0; a11 += q1*k1;
        }
    }
    float* o = Ep + ((size_t)s * BB + b) * (DD * DD);
    o[d0*DD + e0]       = a00;
    o[d0*DD + e0 + 1]   = a01;
    o[(d0+1)*DD + e0]   = a10;
    o[(d0+1)*DD + e0+1] = a11;
}

// ---------------------------------------------------------------------------
// K3: softmax (unchanged).
// ---------------------------------------------------------------------------
__global__ __launch_bounds__(1024) void softmax_kernel(
    const float* __restrict__ Ep, float* __restrict__ attT)
{
    const int b = blockIdx.x;
    const int e = threadIdx.x, d = threadIdx.y;
    float s = 0.f;
    for (int p = 0; p < 64; ++p)
        s += Ep[((size_t)p * BB + b) * (DD * DD) + d * DD + e];
    float nv = -s;
    float m = nv;
    for (int off = 16; off > 0; off >>= 1) m = fmaxf(m, __shfl_xor(m, off, 32));
    float pe = expf(nv - m);
    float su = pe;
    for (int off = 16; off > 0; off >>= 1) su += __shfl_xor(su, off, 32);
    attT[(size_t)b * (DD * DD) + e * DD + d] = pe / su;
}

// ---------------------------------------------------------------------------
// K4: PV — now writes bf16 AOT in [b][130][130][40] padded layout.
// ---------------------------------------------------------------------------
__global__ __launch_bounds__(256) void pv_kernel(
    const float* __restrict__ V, const float* __restrict__ attT,
    unsigned short* __restrict__ AOT)
{
    __shared__ float Vs[DD][256];
    __shared__ float at4[DD][DD];
    const int b  = blockIdx.y;
    const int n0 = blockIdx.x * 256;
    for (int i = threadIdx.x; i < DD * 256; i += 256) {
        int r = i >> 8, cc = i & 255;
        Vs[r][cc] = V[((size_t)b * DD + r) * NN + n0 + cc];
    }
    for (int i = threadIdx.x; i < DD * DD; i += 256)
        at4[i >> 5][i & 31] = attT[(size_t)b * (DD * DD) + i];
    __syncthreads();
    const int t = threadIdx.x;
    float acc[DD];
    #pragma unroll
    for (int d = 0; d < DD; ++d) acc[d] = 0.f;
    #pragma unroll 4
    for (int e = 0; e < DD; ++e) {
        float v = Vs[e][t];
        const float4* ar = (const float4*)at4[e];
        #pragma unroll
        for (int dq = 0; dq < 8; ++dq) {
            float4 a = ar[dq];
            acc[4*dq+0] += a.x * v; acc[4*dq+1] += a.y * v;
            acc[4*dq+2] += a.z * v; acc[4*dq+3] += a.w * v;
        }
    }
    const int n = n0 + t;
    const int h = n >> 7, w = n & 127;
    unsigned short* dst = AOT + (size_t)b*AOT_IMGE + (size_t)(h+1)*AOT_ROWE
                              + (size_t)(w+1)*AOT_CI;
    #pragma unroll
    for (int dq = 0; dq < 8; ++dq) {
        ushort4 u;
        u.x = f2bf(acc[4*dq+0]); u.y = f2bf(acc[4*dq+1]);
        u.z = f2bf(acc[4*dq+2]); u.w = f2bf(acc[4*dq+3]);
        *(ushort4*)(dst + 4*dq) = u;
    }
}

// ---------------------------------------------------------------------------
// K4b: weight repack  wp fp32 [co][ci][3][3] -> Wt bf16 [kk=3*kh+kw][co][40ci]
// ---------------------------------------------------------------------------
__global__ __launch_bounds__(256) void wrepack_kernel(
    const float* __restrict__ wp, unsigned short* __restrict__ Wt)
{
    int i = blockIdx.x * 256 + threadIdx.x;     // 9*256*32 = 73728
    if (i >= 9*256*32) return;
    int kk = i / (256*32);
    int r  = i % (256*32);
    int co = r >> 5, ci = r & 31;
    float v = wp[((size_t)co*32 + ci)*9 + kk];
    Wt[((size_t)kk*256 + co)*AOT_CI + ci] = f2bf(v);
}

// ---------------------------------------------------------------------------
// K5: conv as implicit GEMM via bf16 MFMA.
// grid (H=128 rows, B=4).  Block 256 = 4 waves; tile 256co x 128n (one row).
// K = 9 taps x 32 ci; per K-step the B-operand is the LDS patch shifted by
// (kh-1, kw-1).  Patch = 3 padded AOT rows, staged once, linear copy.
// A (weights) double-buffered per tap.  Frag layouts per m89/m91.
// ---------------------------------------------------------------------------
__global__ __launch_bounds__(256, 2) void conv_kernel(
    const unsigned short* __restrict__ AOT, const unsigned short* __restrict__ Wt,
    const float* __restrict__ gammap, const float* __restrict__ x,
    float* __restrict__ out)
{
    __shared__ __align__(16) char lds[LDS_PATCH + 2*A_SLAB];
    const int b   = blockIdx.y;
    const int h   = blockIdx.x;
    const int tid = threadIdx.x;
    const int wid = tid >> 6;
    const int lane = tid & 63;
    const int l15 = lane & 15;
    const int jblk = lane >> 4;

    // stage patch: rows (h-1..h+1) in padded coords = AOT[b][h..h+2][*][*]
    const char* psrc = (const char*)(AOT + (size_t)b*AOT_IMGE + (size_t)h*AOT_ROWE);
    for (int r = wid; r < 31; r += 4)
        async_copy16(lds + r*1024, psrc + r*1024 + lane*16);
    // stage A for kk=0 into slab 0
    {
        const char* asrc = (const char*)Wt;
        for (int r = wid; r < 20; r += 4)
            async_copy16(lds + LDS_PATCH + r*1024, asrc + r*1024 + lane*16);
    }
    __syncthreads();

    f32x4 acc[4][8];
    #pragma unroll
    for (int cf = 0; cf < 4; ++cf)
        #pragma unroll
        for (int nf = 0; nf < 8; ++nf)
            acc[cf][nf] = (f32x4){0.f, 0.f, 0.f, 0.f};

    for (int kk = 0; kk < 9; ++kk) {
        const int cur = kk & 1;
        if (kk < 8) {                       // prefetch next tap's weights
            const char* asrc = (const char*)Wt + (size_t)(kk+1)*A_SLAB;
            char* adst = lds + LDS_PATCH + (cur^1)*A_SLAB;
            for (int r = wid; r < 20; r += 4)
                async_copy16(adst + r*1024, asrc + r*1024 + lane*16);
        }
        const int kh = kk / 3, kw = kk % 3;
        const char* abase = lds + LDS_PATCH + cur*A_SLAB;
        bf16x8 af[4];
        #pragma unroll
        for (int cf = 0; cf < 4; ++cf)
            af[cf] = *(const bf16x8*)(abase + (wid*64 + cf*16 + l15)*80 + jblk*16);
        #pragma unroll
        for (int nf = 0; nf < 8; ++nf) {
            const bf16x8 bfr = *(const bf16x8*)(lds
                                + (kh*130 + nf*16 + l15 + kw)*80 + jblk*16);
            #pragma unroll
            for (int cf = 0; cf < 4; ++cf)
                acc[cf][nf] = __builtin_amdgcn_mfma_f32_16x16x32_bf16(
                    af[cf], bfr, acc[cf][nf], 0, 0, 0);
        }
        __syncthreads();
    }

    const float g0 = gammap[0];
    #pragma unroll
    for (int cf = 0; cf < 4; ++cf) {
        #pragma unroll
        for (int nf = 0; nf < 8; ++nf) {
            #pragma unroll
            for (int j = 0; j < 4; ++j) {
                const int co = wid*64 + cf*16 + jblk*4 + j;
                const int wc = nf*16 + l15;
                const size_t o = ((size_t)b*CC + co)*NN + (size_t)h*WW + wc;
                const float v  = acc[cf][nf][j];
                const float ge = 0.5f * v * (1.0f + erff(v * 0.70710678118654752f));
                out[o] = g0 * ge + x[o];
            }
        }
    }
}

// ---------------------------------------------------------------------------
extern "C" void kernel_launch(void* const* d_in, const int* in_sizes, int n_in,
                              void* d_out, int out_size, void* d_ws, size_t ws_size,
                              hipStream_t stream)
{
    const float* x  = (const float*)d_in[0];
    const float* wq = (const float*)d_in[1];
    const float* bq = (const float*)d_in[2];
    const float* wk = (const float*)d_in[3];
    const float* bk = (const float*)d_in[4];
    const float* wv = (const float*)d_in[5];
    const float* bv = (const float*)d_in[6];
    const float* wp = (const float*)d_in[7];
    const float* gm = (const float*)d_in[8];
    float* out = (float*)d_out;

    // Q/K/V scratch aliased into d_out (conv overwrites d_out last).
    float* Qb = out;
    float* Kb = out + (size_t)2097152;
    float* Vb = out + (size_t)4194304;

    char* ws = (char*)d_ws;
    unsigned short* AOT = (unsigned short*)ws;                 // AOT_ALLOC bytes
    unsigned short* Wt  = (unsigned short*)(ws + AOT_ALLOC);   // WT_BYTES
    float* Ep  = (float*)(ws + AOT_ALLOC + WT_BYTES);          // 262144 floats
    float* ATT = Ep + 262144;                                  // 4096 floats

    hipMemsetAsync(AOT, 0, AOT_ALLOC, stream);   // zero borders (+slack, +pads)
    wrepack_kernel<<<dim3((9*256*32 + 255)/256), 256, 0, stream>>>(wp, Wt);
    qkv_kernel    <<<dim3(NN/64, BB), 256, 0, stream>>>(x, wq, bq, wk, bk, wv, bv, Qb, Kb, Vb);
    energy_kernel <<<dim3(64, BB), 256, 0, stream>>>(Qb, Kb, Ep);
    softmax_kernel<<<dim3(BB), dim3(32, 32), 0, stream>>>(Ep, ATT);
    pv_kernel     <<<dim3(NN/256, BB), 256, 0, stream>>>(Vb, ATT, AOT);
    conv_kernel   <<<dim3(HH, BB), 256, 0, stream>>>(AOT, Wt, gm, x, out);
}

// Round 3
// 151.402 us; speedup vs baseline: 5.5339x; 1.9012x over previous
//
#include <hip/hip_runtime.h>
#include <hip/hip_bf16.h>
#include <math.h>

#define BB 4
#define CC 256
#define HH 128
#define WW 128
#define NN (HH*WW)
#define DD 32

// AOT: attention output, bf16, spatially padded +1 border, ci padded 32->40.
// Layout [b][130 rows][130 cols][40 ci]  (border rows/cols zeroed by memset)
#define AOT_CI   40
#define AOT_ROWE (130*AOT_CI)            // elems per padded row (5200)
#define AOT_IMGE (130*AOT_ROWE)          // elems per batch (676000)
#define AOT_BYTES ((size_t)BB*AOT_IMGE*2)      // 5,408,000
#define AOT_ALLOC (AOT_BYTES + 1024)           // slack for linear-copy overrun

#define WT_BYTES (9*256*AOT_CI*2)        // 184,320
#define LDS_PATCH 31744                  // 31 x 1024 (covers 3*130*80 = 31200)
#define A_SLAB    20480                  // 256*80

typedef __attribute__((ext_vector_type(8))) short bf16x8;
typedef __attribute__((ext_vector_type(4))) float f32x4;

__device__ inline void async_copy16(void* lds, const void* g) {
    __builtin_amdgcn_global_load_lds(
        (const __attribute__((address_space(1))) unsigned int*)g,
        (__attribute__((address_space(3))) unsigned int*)lds, 16, 0, 0);
}

__device__ inline unsigned short f2bf(float f) {
    __hip_bfloat16 h = __float2bfloat16(f);
    return *reinterpret_cast<unsigned short*>(&h);
}

// ---------------------------------------------------------------------------
// K1: QKV projection, restructured for FMA density.
// Output stacked: QKV[b][96][N]  (rows 0-31 = Q, 32-63 = K, 64-95 = V).
// grid (N/128, B), block 512 = 8 waves; wave w owns rows 12w..12w+11.
// Thread: 2 n-columns (float2), 24 fp32 accums.
// W (96x256 fp32, 96KB) + biases staged once in LDS; inner loop per c-quad:
// 12 wave-uniform ds_read_b128 + 4 global float2 + 96 FMA  (~86% density).
// ---------------------------------------------------------------------------
__global__ __launch_bounds__(512, 1) void qkv_kernel(
    const float* __restrict__ x,
    const float* __restrict__ wq, const float* __restrict__ bq,
    const float* __restrict__ wk, const float* __restrict__ bk,
    const float* __restrict__ wv, const float* __restrict__ bv,
    float* __restrict__ QKV)
{
    __shared__ __align__(16) float Wl[96][256];   // 96 KB
    __shared__ float Bl[96];
    const int b    = blockIdx.y;
    const int n0   = blockIdx.x * 128;
    const int tid  = threadIdx.x;
    const int wid  = tid >> 6;
    const int lane = tid & 63;

    // stage stacked weights: 3 arrays x 32 rows x 1KB, linear global_load_lds
    {
        const float* srcs[3] = { wq, wk, wv };
        #pragma unroll
        for (int m = 0; m < 3; ++m)
            for (int r = wid; r < 32; r += 8)
                async_copy16(&Wl[m*32 + r][0], srcs[m] + r*256 + lane*4);
    }
    if (tid < 96)
        Bl[tid] = (tid < 32) ? bq[tid] : (tid < 64) ? bk[tid-32] : bv[tid-64];
    __syncthreads();

    const int n = n0 + lane*2;
    const float* xb = x + (size_t)b*CC*NN + n;
    const int r0 = wid * 12;

    float accx[12], accy[12];
    #pragma unroll
    for (int i = 0; i < 12; ++i) { accx[i] = 0.f; accy[i] = 0.f; }

    #pragma unroll 2
    for (int cq = 0; cq < 64; ++cq) {
        const int c = cq * 4;
        float2 x0 = *(const float2*)(xb + (size_t)(c  )*NN);
        float2 x1 = *(const float2*)(xb + (size_t)(c+1)*NN);
        float2 x2 = *(const float2*)(xb + (size_t)(c+2)*NN);
        float2 x3 = *(const float2*)(xb + (size_t)(c+3)*NN);
        #pragma unroll
        for (int i = 0; i < 12; ++i) {
            float4 w = *(const float4*)&Wl[r0 + i][c];
            accx[i] += w.x*x0.x + w.y*x1.x + w.z*x2.x + w.w*x3.x;
            accy[i] += w.x*x0.y + w.y*x1.y + w.z*x2.y + w.w*x3.y;
        }
    }
    #pragma unroll
    for (int i = 0; i < 12; ++i) {
        const int r = r0 + i;
        float2 o;
        o.x = accx[i] + Bl[r];
        o.y = accy[i] + Bl[r];
        *(float2*)(QKV + ((size_t)b*96 + r)*NN + n) = o;
    }
}

// ---------------------------------------------------------------------------
// K2: partial energy (reads stacked QKV: Q rows +0, K rows +32).
// ---------------------------------------------------------------------------
__global__ __launch_bounds__(256) void energy_kernel(
    const float* __restrict__ QKV, float* __restrict__ Ep)
{
    __shared__ float Qs[DD][130];
    __shared__ float Ks[DD][130];
    const int b  = blockIdx.y;
    const int s  = blockIdx.x;
    const int n0 = s * 256;
    const int d0 = (threadIdx.x >> 4) * 2;
    const int e0 = (threadIdx.x & 15) * 2;
    float a00 = 0.f, a01 = 0.f, a10 = 0.f, a11 = 0.f;
    for (int sc = 0; sc < 2; ++sc) {
        __syncthreads();
        for (int i = threadIdx.x; i < DD * 128; i += 256) {
            int r = i >> 7, cc = i & 127;
            size_t idx = (size_t)(n0 + sc * 128 + cc);
            Qs[r][cc] = QKV[((size_t)(b*96     ) + r)*NN + idx];
            Ks[r][cc] = QKV[((size_t)(b*96 + 32) + r)*NN + idx];
        }
        __syncthreads();
        for (int nn = 0; nn < 128; ++nn) {
            float q0 = Qs[d0][nn], q1 = Qs[d0+1][nn];
            float k0 = Ks[e0][nn], k1 = Ks[e0+1][nn];
            a00 += q0*k0; a01 += q0*k1; a10 += q1*k0; a11 += q1*k1;
        }
    }
    float* o = Ep + ((size_t)s * BB + b) * (DD * DD);
    o[d0*DD + e0]       = a00;
    o[d0*DD + e0 + 1]   = a01;
    o[(d0+1)*DD + e0]   = a10;
    o[(d0+1)*DD + e0+1] = a11;
}

// ---------------------------------------------------------------------------
// K3: softmax (unchanged).
// ---------------------------------------------------------------------------
__global__ __launch_bounds__(1024) void softmax_kernel(
    const float* __restrict__ Ep, float* __restrict__ attT)
{
    const int b = blockIdx.x;
    const int e = threadIdx.x, d = threadIdx.y;
    float s = 0.f;
    for (int p = 0; p < 64; ++p)
        s += Ep[((size_t)p * BB + b) * (DD * DD) + d * DD + e];
    float nv = -s;
    float m = nv;
    for (int off = 16; off > 0; off >>= 1) m = fmaxf(m, __shfl_xor(m, off, 32));
    float pe = expf(nv - m);
    float su = pe;
    for (int off = 16; off > 0; off >>= 1) su += __shfl_xor(su, off, 32);
    attT[(size_t)b * (DD * DD) + e * DD + d] = pe / su;
}

// ---------------------------------------------------------------------------
// K4: PV (reads stacked QKV: V rows +64) — writes bf16 AOT padded layout.
// ---------------------------------------------------------------------------
__global__ __launch_bounds__(256) void pv_kernel(
    const float* __restrict__ QKV, const float* __restrict__ attT,
    unsigned short* __restrict__ AOT)
{
    __shared__ float Vs[DD][256];
    __shared__ float at4[DD][DD];
    const int b  = blockIdx.y;
    const int n0 = blockIdx.x * 256;
    for (int i = threadIdx.x; i < DD * 256; i += 256) {
        int r = i >> 8, cc = i & 255;
        Vs[r][cc] = QKV[((size_t)(b*96 + 64) + r)*NN + n0 + cc];
    }
    for (int i = threadIdx.x; i < DD * DD; i += 256)
        at4[i >> 5][i & 31] = attT[(size_t)b * (DD * DD) + i];
    __syncthreads();
    const int t = threadIdx.x;
    float acc[DD];
    #pragma unroll
    for (int d = 0; d < DD; ++d) acc[d] = 0.f;
    #pragma unroll 4
    for (int e = 0; e < DD; ++e) {
        float v = Vs[e][t];
        const float4* ar = (const float4*)at4[e];
        #pragma unroll
        for (int dq = 0; dq < 8; ++dq) {
            float4 a = ar[dq];
            acc[4*dq+0] += a.x * v; acc[4*dq+1] += a.y * v;
            acc[4*dq+2] += a.z * v; acc[4*dq+3] += a.w * v;
        }
    }
    const int n = n0 + t;
    const int h = n >> 7, w = n & 127;
    unsigned short* dst = AOT + (size_t)b*AOT_IMGE + (size_t)(h+1)*AOT_ROWE
                              + (size_t)(w+1)*AOT_CI;
    #pragma unroll
    for (int dq = 0; dq < 8; ++dq) {
        ushort4 u;
        u.x = f2bf(acc[4*dq+0]); u.y = f2bf(acc[4*dq+1]);
        u.z = f2bf(acc[4*dq+2]); u.w = f2bf(acc[4*dq+3]);
        *(ushort4*)(dst + 4*dq) = u;
    }
}

// ---------------------------------------------------------------------------
// K4b: weight repack  wp fp32 [co][ci][3][3] -> Wt bf16 [kk=3*kh+kw][co][40ci]
// ---------------------------------------------------------------------------
__global__ __launch_bounds__(256) void wrepack_kernel(
    const float* __restrict__ wp, unsigned short* __restrict__ Wt)
{
    int i = blockIdx.x * 256 + threadIdx.x;     // 9*256*32 = 73728
    if (i >= 9*256*32) return;
    int kk = i / (256*32);
    int r  = i % (256*32);
    int co = r >> 5, ci = r & 31;
    float v = wp[((size_t)co*32 + ci)*9 + kk];
    Wt[((size_t)kk*256 + co)*AOT_CI + ci] = f2bf(v);
}

// ---------------------------------------------------------------------------
// K5: conv as implicit GEMM via bf16 MFMA (unchanged from round 2).
// ---------------------------------------------------------------------------
__global__ __launch_bounds__(256, 2) void conv_kernel(
    const unsigned short* __restrict__ AOT, const unsigned short* __restrict__ Wt,
    const float* __restrict__ gammap, const float* __restrict__ x,
    float* __restrict__ out)
{
    __shared__ __align__(16) char lds[LDS_PATCH + 2*A_SLAB];
    const int b   = blockIdx.y;
    const int h   = blockIdx.x;
    const int tid = threadIdx.x;
    const int wid = tid >> 6;
    const int lane = tid & 63;
    const int l15 = lane & 15;
    const int jblk = lane >> 4;

    const char* psrc = (const char*)(AOT + (size_t)b*AOT_IMGE + (size_t)h*AOT_ROWE);
    for (int r = wid; r < 31; r += 4)
        async_copy16(lds + r*1024, psrc + r*1024 + lane*16);
    {
        const char* asrc = (const char*)Wt;
        for (int r = wid; r < 20; r += 4)
            async_copy16(lds + LDS_PATCH + r*1024, asrc + r*1024 + lane*16);
    }
    __syncthreads();

    f32x4 acc[4][8];
    #pragma unroll
    for (int cf = 0; cf < 4; ++cf)
        #pragma unroll
        for (int nf = 0; nf < 8; ++nf)
            acc[cf][nf] = (f32x4){0.f, 0.f, 0.f, 0.f};

    for (int kk = 0; kk < 9; ++kk) {
        const int cur = kk & 1;
        if (kk < 8) {
            const char* asrc = (const char*)Wt + (size_t)(kk+1)*A_SLAB;
            char* adst = lds + LDS_PATCH + (cur^1)*A_SLAB;
            for (int r = wid; r < 20; r += 4)
                async_copy16(adst + r*1024, asrc + r*1024 + lane*16);
        }
        const int kh = kk / 3, kw = kk % 3;
        const char* abase = lds + LDS_PATCH + cur*A_SLAB;
        bf16x8 af[4];
        #pragma unroll
        for (int cf = 0; cf < 4; ++cf)
            af[cf] = *(const bf16x8*)(abase + (wid*64 + cf*16 + l15)*80 + jblk*16);
        #pragma unroll
        for (int nf = 0; nf < 8; ++nf) {
            const bf16x8 bfr = *(const bf16x8*)(lds
                                + (kh*130 + nf*16 + l15 + kw)*80 + jblk*16);
            #pragma unroll
            for (int cf = 0; cf < 4; ++cf)
                acc[cf][nf] = __builtin_amdgcn_mfma_f32_16x16x32_bf16(
                    af[cf], bfr, acc[cf][nf], 0, 0, 0);
        }
        __syncthreads();
    }

    const float g0 = gammap[0];
    #pragma unroll
    for (int cf = 0; cf < 4; ++cf) {
        #pragma unroll
        for (int nf = 0; nf < 8; ++nf) {
            #pragma unroll
            for (int j = 0; j < 4; ++j) {
                const int co = wid*64 + cf*16 + jblk*4 + j;
                const int wc = nf*16 + l15;
                const size_t o = ((size_t)b*CC + co)*NN + (size_t)h*WW + wc;
                const float v  = acc[cf][nf][j];
                const float ge = 0.5f * v * (1.0f + erff(v * 0.70710678118654752f));
                out[o] = g0 * ge + x[o];
            }
        }
    }
}

// ---------------------------------------------------------------------------
extern "C" void kernel_launch(void* const* d_in, const int* in_sizes, int n_in,
                              void* d_out, int out_size, void* d_ws, size_t ws_size,
                              hipStream_t stream)
{
    const float* x  = (const float*)d_in[0];
    const float* wq = (const float*)d_in[1];
    const float* bq = (const float*)d_in[2];
    const float* wk = (const float*)d_in[3];
    const float* bk = (const float*)d_in[4];
    const float* wv = (const float*)d_in[5];
    const float* bv = (const float*)d_in[6];
    const float* wp = (const float*)d_in[7];
    const float* gm = (const float*)d_in[8];
    float* out = (float*)d_out;

    // Stacked QKV scratch aliased into d_out (conv overwrites d_out last).
    float* QKV = out;                              // 4*96*16384 floats = 25 MB

    char* ws = (char*)d_ws;
    unsigned short* AOT = (unsigned short*)ws;                 // AOT_ALLOC bytes
    unsigned short* Wt  = (unsigned short*)(ws + AOT_ALLOC);   // WT_BYTES
    float* Ep  = (float*)(ws + AOT_ALLOC + WT_BYTES);          // 262144 floats
    float* ATT = Ep + 262144;                                  // 4096 floats

    hipMemsetAsync(AOT, 0, AOT_ALLOC, stream);
    wrepack_kernel<<<dim3((9*256*32 + 255)/256), 256, 0, stream>>>(wp, Wt);
    qkv_kernel    <<<dim3(NN/128, BB), 512, 0, stream>>>(x, wq, bq, wk, bk, wv, bv, QKV);
    energy_kernel <<<dim3(64, BB), 256, 0, stream>>>(QKV, Ep);
    softmax_kernel<<<dim3(BB), dim3(32, 32), 0, stream>>>(Ep, ATT);
    pv_kernel     <<<dim3(NN/256, BB), 256, 0, stream>>>(QKV, ATT, AOT);
    conv_kernel   <<<dim3(HH, BB), 256, 0, stream>>>(AOT, Wt, gm, x, out);
}

// Round 4
// 115.580 us; speedup vs baseline: 7.2490x; 1.3099x over previous
//
#include <hip/hip_runtime.h>
#include <hip/hip_bf16.h>
#include <math.h>

#define BB 4
#define CC 256
#define HH 128
#define WW 128
#define NN (HH*WW)
#define DD 32

// AOT: attention output, bf16, spatially padded +1 border, ci padded 32->40.
#define AOT_CI   40
#define AOT_ROWE (130*AOT_CI)
#define AOT_IMGE (130*AOT_ROWE)
#define AOT_BYTES ((size_t)BB*AOT_IMGE*2)      // 5,408,000
#define AOT_ALLOC (AOT_BYTES + 1024)           // 5,409,024 (16-aligned)

#define WT_BYTES (9*256*AOT_CI*2)        // 184,320
#define LDS_PATCH 31744
#define A_SLAB    20480

// qkv_mfma geometry
#define BPITCH 272            // B-tile row pitch bytes (136 shorts)
#define AQ_OFF 69632          // A region offset in lds (256*272)
#define ACH    26112          // bytes per A slab-chunk (96*272)
#define APACK_BYTES (4*2*ACH) // 208,896
#define QKP    260            // QK lds row pitch (floats)

typedef __attribute__((ext_vector_type(8))) short bf16x8;
typedef __attribute__((ext_vector_type(4))) float f32x4;

__device__ inline void async_copy16(void* lds, const void* g) {
    __builtin_amdgcn_global_load_lds(
        (const __attribute__((address_space(1))) unsigned int*)g,
        (__attribute__((address_space(3))) unsigned int*)lds, 16, 0, 0);
}

__device__ inline unsigned short f2bf(float f) {
    __hip_bfloat16 h = __float2bfloat16(f);
    return *reinterpret_cast<unsigned short*>(&h);
}

__device__ inline void split2(float v, unsigned short& h, unsigned short& l) {
    __hip_bfloat16 hb = __float2bfloat16(v);
    float r = v - __bfloat162float(hb);     // exact (Sterbenz)
    __hip_bfloat16 lb = __float2bfloat16(r);
    h = *reinterpret_cast<unsigned short*>(&hb);
    l = *reinterpret_cast<unsigned short*>(&lb);
}

// ---------------------------------------------------------------------------
// K0a: pack W (stacked q,k,v rows 0-95) into split-bf16 A images per K-chunk:
// Apack[q][slab hi/lo][96 m][136 shorts]; slots 2j,2j+1 duplicate the value
// (B slots are [x_hi, x_lo] per c).  Pads (shorts 128..135) zeroed.
// ---------------------------------------------------------------------------
__global__ __launch_bounds__(256) void wrepack2_kernel(
    const float* __restrict__ wq, const float* __restrict__ wk,
    const float* __restrict__ wv, unsigned short* __restrict__ Apack)
{
    int i = blockIdx.x * 256 + threadIdx.x;      // 4*96*68 = 26112 tasks
    if (i >= 4*96*68) return;
    int q = i / (96*68);
    int r = i % (96*68);
    int m = r / 68, j = r % 68;
    unsigned short h = 0, l = 0;
    if (j < 64) {
        int c = 64*q + j;
        float w = (m < 32) ? wq[m*256 + c]
                : (m < 64) ? wk[(m-32)*256 + c]
                           : wv[(m-64)*256 + c];
        split2(w, h, l);
    }
    size_t oh = ((size_t)(q*2 + 0)*96 + m)*136 + 2*j;
    size_t ol = ((size_t)(q*2 + 1)*96 + m)*136 + 2*j;
    Apack[oh] = h; Apack[oh+1] = h;
    Apack[ol] = l; Apack[ol+1] = l;
}

// ---------------------------------------------------------------------------
// K1: QKV via split-bf16 MFMA GEMM (M=96, K=512 slots, N=256/block) with
// fused energy partial.  grid (64 n-tiles, B), 512 thr = 8 waves (2m x 4n).
// Per chunk: stage A (global_load_lds linear) + B (x fp32 -> split bf16,
// ds_write_b128), then 4 K-steps x (10 ds_read_b128 + 24 MFMA)/wave.
// Epilogue: Q,K rows (+bias) -> LDS, V rows (+bias) -> global;
// E_part[32][32] = sum_n Q K over this block's 256 n -> Ep[s][b].
// ---------------------------------------------------------------------------
__global__ __launch_bounds__(512, 1) void qkv_mfma_kernel(
    const float* __restrict__ x, const unsigned short* __restrict__ Apack,
    const float* __restrict__ bq, const float* __restrict__ bk,
    const float* __restrict__ bv,
    float* __restrict__ Vout, float* __restrict__ Ep)
{
    __shared__ __align__(16) char lds[AQ_OFF + 2*ACH];   // 121,856 B
    __shared__ float biasL[96];
    const int b   = blockIdx.y;
    const int s   = blockIdx.x;
    const int n0  = s * 256;
    const int tid = threadIdx.x;
    const int lane = tid & 63;
    const int wid  = tid >> 6;
    const int wm = wid >> 2, wn = wid & 3;
    const int l15 = lane & 15, lj = lane >> 4;

    if (tid < 96)
        biasL[tid] = (tid < 32) ? bq[tid] : (tid < 64) ? bk[tid-32] : bv[tid-64];

    const float* xb = x + (size_t)b*CC*NN + n0;

    f32x4 acc[3][4];
    #pragma unroll
    for (int cf = 0; cf < 3; ++cf)
        #pragma unroll
        for (int nf = 0; nf < 4; ++nf)
            acc[cf][nf] = (f32x4){0.f, 0.f, 0.f, 0.f};

    for (int q = 0; q < 4; ++q) {
        __syncthreads();                      // protect LDS from prior phase
        // stage A chunk (hi+lo slabs, contiguous 52,224 B), linear copy
        {
            const char* src = (const char*)Apack + (size_t)q*2*ACH;
            for (int i = tid; i < 3264; i += 512)
                async_copy16(lds + AQ_OFF + i*16, src + i*16);
        }
        // stage B chunk: c in [64q, 64q+64), convert fp32 -> (hi,lo) pairs
        for (int i = tid; i < 4096; i += 512) {
            int cq = i >> 8, n = i & 255;
            const float* xp = xb + (size_t)(64*q + 4*cq)*NN + n;
            float x0 = xp[0], x1 = xp[NN], x2 = xp[2*NN], x3 = xp[3*NN];
            union { bf16x8 v; unsigned short u[8]; } pk;
            split2(x0, pk.u[0], pk.u[1]);
            split2(x1, pk.u[2], pk.u[3]);
            split2(x2, pk.u[4], pk.u[5]);
            split2(x3, pk.u[6], pk.u[7]);
            *(bf16x8*)(lds + n*BPITCH + cq*16) = pk.v;
        }
        __syncthreads();
        const char* Ah = lds + AQ_OFF;
        const char* Al = lds + AQ_OFF + ACH;
        #pragma unroll
        for (int st = 0; st < 4; ++st) {
            const int ko = lj*16 + st*64;
            bf16x8 bf[4];
            #pragma unroll
            for (int nf = 0; nf < 4; ++nf)
                bf[nf] = *(const bf16x8*)(lds + (64*wn + 16*nf + l15)*BPITCH + ko);
            #pragma unroll
            for (int cf = 0; cf < 3; ++cf) {
                const int arow = (48*wm + 16*cf + l15)*BPITCH + ko;
                bf16x8 ah = *(const bf16x8*)(Ah + arow);
                bf16x8 al = *(const bf16x8*)(Al + arow);
                #pragma unroll
                for (int nf = 0; nf < 4; ++nf) {
                    acc[cf][nf] = __builtin_amdgcn_mfma_f32_16x16x32_bf16(
                        ah, bf[nf], acc[cf][nf], 0, 0, 0);
                    acc[cf][nf] = __builtin_amdgcn_mfma_f32_16x16x32_bf16(
                        al, bf[nf], acc[cf][nf], 0, 0, 0);
                }
            }
        }
    }

    // ---- epilogue: QK -> LDS (+bias), V -> global (+bias) ----
    __syncthreads();
    float* qk = (float*)lds;                  // [64 rows][QKP floats]
    #pragma unroll
    for (int cf = 0; cf < 3; ++cf) {
        const int rbase = 48*wm + 16*cf + 4*lj;
        #pragma unroll
        for (int nf = 0; nf < 4; ++nf) {
            const int col = 64*wn + 16*nf + l15;
            #pragma unroll
            for (int j = 0; j < 4; ++j) {
                const int row = rbase + j;
                const float v = acc[cf][nf][j] + biasL[row];
                if (row < 64)
                    qk[row*QKP + col] = v;
                else
                    Vout[((size_t)b*DD + (row-64))*NN + n0 + col] = v;
            }
        }
    }
    __syncthreads();

    // ---- energy partial: E[d][e] = sum_n Q[d][n]*K[e][n] ----
    const int d  = tid >> 4;                  // 0..31
    const int e0 = tid & 15;
    const float* qrow = qk + d*QKP;
    const float* ka   = qk + (32 + e0)*QKP;
    const float* kb   = qk + (48 + e0)*QKP;
    float s0 = 0.f, s1 = 0.f;
    for (int n4 = 0; n4 < 256; n4 += 4) {
        float4 qv = *(const float4*)(qrow + n4);
        float4 va = *(const float4*)(ka + n4);
        float4 vb = *(const float4*)(kb + n4);
        s0 += qv.x*va.x + qv.y*va.y + qv.z*va.z + qv.w*va.w;
        s1 += qv.x*vb.x + qv.y*vb.y + qv.z*vb.z + qv.w*vb.w;
    }
    float* ep = Ep + ((size_t)s*BB + b)*1024;
    ep[d*32 + e0]      = s0;
    ep[d*32 + e0 + 16] = s1;
}

// ---------------------------------------------------------------------------
// K3: softmax over reduced partials (64 n-tiles).  softmax(max-E)==softmax(-E).
// ---------------------------------------------------------------------------
__global__ __launch_bounds__(1024) void softmax_kernel(
    const float* __restrict__ Ep, float* __restrict__ attT)
{
    const int b = blockIdx.x;
    const int e = threadIdx.x, d = threadIdx.y;
    float s = 0.f;
    for (int p = 0; p < 64; ++p)
        s += Ep[((size_t)p * BB + b) * (DD * DD) + d * DD + e];
    float nv = -s;
    float m = nv;
    for (int off = 16; off > 0; off >>= 1) m = fmaxf(m, __shfl_xor(m, off, 32));
    float pe = expf(nv - m);
    float su = pe;
    for (int off = 16; off > 0; off >>= 1) su += __shfl_xor(su, off, 32);
    attT[(size_t)b * (DD * DD) + e * DD + d] = pe / su;
}

// ---------------------------------------------------------------------------
// K4: PV (V now standalone [b][32][N]) — writes bf16 AOT padded layout.
// ---------------------------------------------------------------------------
__global__ __launch_bounds__(256) void pv_kernel(
    const float* __restrict__ V, const float* __restrict__ attT,
    unsigned short* __restrict__ AOT)
{
    __shared__ float Vs[DD][256];
    __shared__ float at4[DD][DD];
    const int b  = blockIdx.y;
    const int n0 = blockIdx.x * 256;
    for (int i = threadIdx.x; i < DD * 256; i += 256) {
        int r = i >> 8, cc = i & 255;
        Vs[r][cc] = V[((size_t)b*DD + r)*NN + n0 + cc];
    }
    for (int i = threadIdx.x; i < DD * DD; i += 256)
        at4[i >> 5][i & 31] = attT[(size_t)b * (DD * DD) + i];
    __syncthreads();
    const int t = threadIdx.x;
    float acc[DD];
    #pragma unroll
    for (int d = 0; d < DD; ++d) acc[d] = 0.f;
    #pragma unroll 4
    for (int e = 0; e < DD; ++e) {
        float v = Vs[e][t];
        const float4* ar = (const float4*)at4[e];
        #pragma unroll
        for (int dq = 0; dq < 8; ++dq) {
            float4 a = ar[dq];
            acc[4*dq+0] += a.x * v; acc[4*dq+1] += a.y * v;
            acc[4*dq+2] += a.z * v; acc[4*dq+3] += a.w * v;
        }
    }
    const int n = n0 + t;
    const int h = n >> 7, w = n & 127;
    unsigned short* dst = AOT + (size_t)b*AOT_IMGE + (size_t)(h+1)*AOT_ROWE
                              + (size_t)(w+1)*AOT_CI;
    #pragma unroll
    for (int dq = 0; dq < 8; ++dq) {
        ushort4 u;
        u.x = f2bf(acc[4*dq+0]); u.y = f2bf(acc[4*dq+1]);
        u.z = f2bf(acc[4*dq+2]); u.w = f2bf(acc[4*dq+3]);
        *(ushort4*)(dst + 4*dq) = u;
    }
}

// ---------------------------------------------------------------------------
// K4b: conv weight repack  wp fp32 [co][ci][3][3] -> Wt bf16 [kk][co][40ci]
// ---------------------------------------------------------------------------
__global__ __launch_bounds__(256) void wrepack_kernel(
    const float* __restrict__ wp, unsigned short* __restrict__ Wt)
{
    int i = blockIdx.x * 256 + threadIdx.x;
    if (i >= 9*256*32) return;
    int kk = i / (256*32);
    int r  = i % (256*32);
    int co = r >> 5, ci = r & 31;
    float v = wp[((size_t)co*32 + ci)*9 + kk];
    Wt[((size_t)kk*256 + co)*AOT_CI + ci] = f2bf(v);
}

// ---------------------------------------------------------------------------
// K5: conv as implicit GEMM via bf16 MFMA (unchanged from round 2).
// ---------------------------------------------------------------------------
__global__ __launch_bounds__(256, 2) void conv_kernel(
    const unsigned short* __restrict__ AOT, const unsigned short* __restrict__ Wt,
    const float* __restrict__ gammap, const float* __restrict__ x,
    float* __restrict__ out)
{
    __shared__ __align__(16) char lds[LDS_PATCH + 2*A_SLAB];
    const int b   = blockIdx.y;
    const int h   = blockIdx.x;
    const int tid = threadIdx.x;
    const int wid = tid >> 6;
    const int lane = tid & 63;
    const int l15 = lane & 15;
    const int jblk = lane >> 4;

    const char* psrc = (const char*)(AOT + (size_t)b*AOT_IMGE + (size_t)h*AOT_ROWE);
    for (int r = wid; r < 31; r += 4)
        async_copy16(lds + r*1024, psrc + r*1024 + lane*16);
    {
        const char* asrc = (const char*)Wt;
        for (int r = wid; r < 20; r += 4)
            async_copy16(lds + LDS_PATCH + r*1024, asrc + r*1024 + lane*16);
    }
    __syncthreads();

    f32x4 acc[4][8];
    #pragma unroll
    for (int cf = 0; cf < 4; ++cf)
        #pragma unroll
        for (int nf = 0; nf < 8; ++nf)
            acc[cf][nf] = (f32x4){0.f, 0.f, 0.f, 0.f};

    for (int kk = 0; kk < 9; ++kk) {
        const int cur = kk & 1;
        if (kk < 8) {
            const char* asrc = (const char*)Wt + (size_t)(kk+1)*A_SLAB;
            char* adst = lds + LDS_PATCH + (cur^1)*A_SLAB;
            for (int r = wid; r < 20; r += 4)
                async_copy16(adst + r*1024, asrc + r*1024 + lane*16);
        }
        const int kh = kk / 3, kw = kk % 3;
        const char* abase = lds + LDS_PATCH + cur*A_SLAB;
        bf16x8 af[4];
        #pragma unroll
        for (int cf = 0; cf < 4; ++cf)
            af[cf] = *(const bf16x8*)(abase + (wid*64 + cf*16 + l15)*80 + jblk*16);
        #pragma unroll
        for (int nf = 0; nf < 8; ++nf) {
            const bf16x8 bfr = *(const bf16x8*)(lds
                                + (kh*130 + nf*16 + l15 + kw)*80 + jblk*16);
            #pragma unroll
            for (int cf = 0; cf < 4; ++cf)
                acc[cf][nf] = __builtin_amdgcn_mfma_f32_16x16x32_bf16(
                    af[cf], bfr, acc[cf][nf], 0, 0, 0);
        }
        __syncthreads();
    }

    const float g0 = gammap[0];
    #pragma unroll
    for (int cf = 0; cf < 4; ++cf) {
        #pragma unroll
        for (int nf = 0; nf < 8; ++nf) {
            #pragma unroll
            for (int j = 0; j < 4; ++j) {
                const int co = wid*64 + cf*16 + jblk*4 + j;
                const int wc = nf*16 + l15;
                const size_t o = ((size_t)b*CC + co)*NN + (size_t)h*WW + wc;
                const float v  = acc[cf][nf][j];
                const float ge = 0.5f * v * (1.0f + erff(v * 0.70710678118654752f));
                out[o] = g0 * ge + x[o];
            }
        }
    }
}

// ---------------------------------------------------------------------------
extern "C" void kernel_launch(void* const* d_in, const int* in_sizes, int n_in,
                              void* d_out, int out_size, void* d_ws, size_t ws_size,
                              hipStream_t stream)
{
    const float* x  = (const float*)d_in[0];
    const float* wq = (const float*)d_in[1];
    const float* bq = (const float*)d_in[2];
    const float* wk = (const float*)d_in[3];
    const float* bk = (const float*)d_in[4];
    const float* wv = (const float*)d_in[5];
    const float* bv = (const float*)d_in[6];
    const float* wp = (const float*)d_in[7];
    const float* gm = (const float*)d_in[8];
    float* out = (float*)d_out;

    // V scratch aliased into d_out (pv reads it before conv overwrites out).
    float* Vbuf = out;                               // 4*32*16384 floats

    char* ws = (char*)d_ws;
    unsigned short* AOT   = (unsigned short*)ws;
    unsigned short* Wt    = (unsigned short*)(ws + AOT_ALLOC);
    unsigned short* Apack = (unsigned short*)(ws + AOT_ALLOC + WT_BYTES);
    float* Ep  = (float*)(ws + AOT_ALLOC + WT_BYTES + APACK_BYTES);  // 1 MB
    float* ATT = Ep + 64*BB*1024;

    hipMemsetAsync(AOT, 0, AOT_ALLOC, stream);
    wrepack_kernel <<<dim3(288), 256, 0, stream>>>(wp, Wt);
    wrepack2_kernel<<<dim3((4*96*68 + 255)/256), 256, 0, stream>>>(wq, wk, wv, Apack);
    qkv_mfma_kernel<<<dim3(64, BB), 512, 0, stream>>>(x, Apack, bq, bk, bv, Vbuf, Ep);
    softmax_kernel <<<dim3(BB), dim3(32, 32), 0, stream>>>(Ep, ATT);
    pv_kernel      <<<dim3(NN/256, BB), 256, 0, stream>>>(Vbuf, ATT, AOT);
    conv_kernel    <<<dim3(HH, BB), 256, 0, stream>>>(AOT, Wt, gm, x, out);
}

// Round 5
// 93.296 us; speedup vs baseline: 8.9804x; 1.2388x over previous
//
#include <hip/hip_runtime.h>
#include <hip/hip_bf16.h>
#include <math.h>

#define BB 4
#define CC 256
#define HH 128
#define WW 128
#define NN (HH*WW)
#define DD 32

// AOT: attention output, bf16, spatially padded +1 border, ci padded 32->44.
// 44*2 = 88 B cell pitch -> ds_read_b64 pairs are bank-conflict-free.
#define AOT_CI   44
#define AOT_ROWE (130*AOT_CI)                  // shorts per padded row (5720)
#define AOT_IMGE (130*AOT_ROWE)                // shorts per batch (743600)
#define AOT_BYTES ((size_t)BB*AOT_IMGE*2)      // 5,948,800
#define AOT_ALLOC (AOT_BYTES + 1024)

#define WT_BYTES (9*256*AOT_CI*2)              // 202,752

// conv LDS geometry
#define PATCH_SZ 45760                         // 4 padded rows * 130 * 88
#define WSLAB    22528                         // 256 co * 88
#define CONV_LDS (PATCH_SZ + 2*WSLAB)          // 90,816
#define EPI_PITCH 260                          // floats, epilogue bounce pitch

// qkv_mfma geometry (unchanged from round 4)
#define BPITCH 272
#define AQ_OFF 69632
#define ACH    26112
#define APACK_BYTES (4*2*ACH)
#define QKP    260

typedef __attribute__((ext_vector_type(8))) short bf16x8;
typedef __attribute__((ext_vector_type(4))) float f32x4;

__device__ inline void async_copy16(void* lds, const void* g) {
    __builtin_amdgcn_global_load_lds(
        (const __attribute__((address_space(1))) unsigned int*)g,
        (__attribute__((address_space(3))) unsigned int*)lds, 16, 0, 0);
}

__device__ inline unsigned short f2bf(float f) {
    __hip_bfloat16 h = __float2bfloat16(f);
    return *reinterpret_cast<unsigned short*>(&h);
}

__device__ inline void split2(float v, unsigned short& h, unsigned short& l) {
    __hip_bfloat16 hb = __float2bfloat16(v);
    float r = v - __bfloat162float(hb);     // exact (Sterbenz)
    __hip_bfloat16 lb = __float2bfloat16(r);
    h = *reinterpret_cast<unsigned short*>(&hb);
    l = *reinterpret_cast<unsigned short*>(&lb);
}

// 8B+8B LDS load of a bf16x8 fragment (88B row pitch is only 8B-aligned)
__device__ inline bf16x8 ld_frag8(const char* p) {
    union { bf16x8 v; short4 h[2]; } u;
    u.h[0] = *(const short4*)(p);
    u.h[1] = *(const short4*)(p + 8);
    return u.v;
}

// A&S 7.1.26 erf approximation, |err| ~1e-6 (fits 1e-2-scale budget easily)
__device__ inline float gelu_fast(float v) {
    float a = fabsf(v) * 0.70710678118654752f;
    float t = __fdividef(1.0f, fmaf(0.3275911f, a, 1.0f));
    float p = t * fmaf(t, fmaf(t, fmaf(t, fmaf(t, 1.061405429f, -1.453152027f),
                                       1.421413741f), -0.284496736f), 0.254829592f);
    float e = 1.0f - p * __expf(-a * a);
    float erfv = (v < 0.0f) ? -e : e;
    return 0.5f * v * (1.0f + erfv);
}

// ---------------------------------------------------------------------------
// K0a: pack W (stacked q,k,v) into split-bf16 A images (unchanged).
// ---------------------------------------------------------------------------
__global__ __launch_bounds__(256) void wrepack2_kernel(
    const float* __restrict__ wq, const float* __restrict__ wk,
    const float* __restrict__ wv, unsigned short* __restrict__ Apack)
{
    int i = blockIdx.x * 256 + threadIdx.x;      // 4*96*68 = 26112 tasks
    if (i >= 4*96*68) return;
    int q = i / (96*68);
    int r = i % (96*68);
    int m = r / 68, j = r % 68;
    unsigned short h = 0, l = 0;
    if (j < 64) {
        int c = 64*q + j;
        float w = (m < 32) ? wq[m*256 + c]
                : (m < 64) ? wk[(m-32)*256 + c]
                           : wv[(m-64)*256 + c];
        split2(w, h, l);
    }
    size_t oh = ((size_t)(q*2 + 0)*96 + m)*136 + 2*j;
    size_t ol = ((size_t)(q*2 + 1)*96 + m)*136 + 2*j;
    Apack[oh] = h; Apack[oh+1] = h;
    Apack[ol] = l; Apack[ol+1] = l;
}

// ---------------------------------------------------------------------------
// K1: QKV via split-bf16 MFMA GEMM + fused energy partial (unchanged r4).
// ---------------------------------------------------------------------------
__global__ __launch_bounds__(512, 1) void qkv_mfma_kernel(
    const float* __restrict__ x, const unsigned short* __restrict__ Apack,
    const float* __restrict__ bq, const float* __restrict__ bk,
    const float* __restrict__ bv,
    float* __restrict__ Vout, float* __restrict__ Ep)
{
    __shared__ __align__(16) char lds[AQ_OFF + 2*ACH];
    __shared__ float biasL[96];
    const int b   = blockIdx.y;
    const int s   = blockIdx.x;
    const int n0  = s * 256;
    const int tid = threadIdx.x;
    const int lane = tid & 63;
    const int wid  = tid >> 6;
    const int wm = wid >> 2, wn = wid & 3;
    const int l15 = lane & 15, lj = lane >> 4;

    if (tid < 96)
        biasL[tid] = (tid < 32) ? bq[tid] : (tid < 64) ? bk[tid-32] : bv[tid-64];

    const float* xb = x + (size_t)b*CC*NN + n0;

    f32x4 acc[3][4];
    #pragma unroll
    for (int cf = 0; cf < 3; ++cf)
        #pragma unroll
        for (int nf = 0; nf < 4; ++nf)
            acc[cf][nf] = (f32x4){0.f, 0.f, 0.f, 0.f};

    for (int q = 0; q < 4; ++q) {
        __syncthreads();
        {
            const char* src = (const char*)Apack + (size_t)q*2*ACH;
            for (int i = tid; i < 3264; i += 512)
                async_copy16(lds + AQ_OFF + i*16, src + i*16);
        }
        for (int i = tid; i < 4096; i += 512) {
            int cq = i >> 8, n = i & 255;
            const float* xp = xb + (size_t)(64*q + 4*cq)*NN + n;
            float x0 = xp[0], x1 = xp[NN], x2 = xp[2*NN], x3 = xp[3*NN];
            union { bf16x8 v; unsigned short u[8]; } pk;
            split2(x0, pk.u[0], pk.u[1]);
            split2(x1, pk.u[2], pk.u[3]);
            split2(x2, pk.u[4], pk.u[5]);
            split2(x3, pk.u[6], pk.u[7]);
            *(bf16x8*)(lds + n*BPITCH + cq*16) = pk.v;
        }
        __syncthreads();
        const char* Ah = lds + AQ_OFF;
        const char* Al = lds + AQ_OFF + ACH;
        #pragma unroll
        for (int st = 0; st < 4; ++st) {
            const int ko = lj*16 + st*64;
            bf16x8 bf[4];
            #pragma unroll
            for (int nf = 0; nf < 4; ++nf)
                bf[nf] = *(const bf16x8*)(lds + (64*wn + 16*nf + l15)*BPITCH + ko);
            #pragma unroll
            for (int cf = 0; cf < 3; ++cf) {
                const int arow = (48*wm + 16*cf + l15)*BPITCH + ko;
                bf16x8 ah = *(const bf16x8*)(Ah + arow);
                bf16x8 al = *(const bf16x8*)(Al + arow);
                #pragma unroll
                for (int nf = 0; nf < 4; ++nf) {
                    acc[cf][nf] = __builtin_amdgcn_mfma_f32_16x16x32_bf16(
                        ah, bf[nf], acc[cf][nf], 0, 0, 0);
                    acc[cf][nf] = __builtin_amdgcn_mfma_f32_16x16x32_bf16(
                        al, bf[nf], acc[cf][nf], 0, 0, 0);
                }
            }
        }
    }

    __syncthreads();
    float* qk = (float*)lds;
    #pragma unroll
    for (int cf = 0; cf < 3; ++cf) {
        const int rbase = 48*wm + 16*cf + 4*lj;
        #pragma unroll
        for (int nf = 0; nf < 4; ++nf) {
            const int col = 64*wn + 16*nf + l15;
            #pragma unroll
            for (int j = 0; j < 4; ++j) {
                const int row = rbase + j;
                const float v = acc[cf][nf][j] + biasL[row];
                if (row < 64)
                    qk[row*QKP + col] = v;
                else
                    Vout[((size_t)b*DD + (row-64))*NN + n0 + col] = v;
            }
        }
    }
    __syncthreads();

    const int d  = tid >> 4;
    const int e0 = tid & 15;
    const float* qrow = qk + d*QKP;
    const float* ka   = qk + (32 + e0)*QKP;
    const float* kb   = qk + (48 + e0)*QKP;
    float s0 = 0.f, s1 = 0.f;
    for (int n4 = 0; n4 < 256; n4 += 4) {
        float4 qv = *(const float4*)(qrow + n4);
        float4 va = *(const float4*)(ka + n4);
        float4 vb = *(const float4*)(kb + n4);
        s0 += qv.x*va.x + qv.y*va.y + qv.z*va.z + qv.w*va.w;
        s1 += qv.x*vb.x + qv.y*vb.y + qv.z*vb.z + qv.w*vb.w;
    }
    float* ep = Ep + ((size_t)s*BB + b)*1024;
    ep[d*32 + e0]      = s0;
    ep[d*32 + e0 + 16] = s1;
}

// ---------------------------------------------------------------------------
// K3: softmax (unchanged).
// ---------------------------------------------------------------------------
__global__ __launch_bounds__(1024) void softmax_kernel(
    const float* __restrict__ Ep, float* __restrict__ attT)
{
    const int b = blockIdx.x;
    const int e = threadIdx.x, d = threadIdx.y;
    float s = 0.f;
    for (int p = 0; p < 64; ++p)
        s += Ep[((size_t)p * BB + b) * (DD * DD) + d * DD + e];
    float nv = -s;
    float m = nv;
    for (int off = 16; off > 0; off >>= 1) m = fmaxf(m, __shfl_xor(m, off, 32));
    float pe = expf(nv - m);
    float su = pe;
    for (int off = 16; off > 0; off >>= 1) su += __shfl_xor(su, off, 32);
    attT[(size_t)b * (DD * DD) + e * DD + d] = pe / su;
}

// ---------------------------------------------------------------------------
// K4: PV — writes bf16 AOT padded layout (ci pitch 44 now).
// ---------------------------------------------------------------------------
__global__ __launch_bounds__(256) void pv_kernel(
    const float* __restrict__ V, const float* __restrict__ attT,
    unsigned short* __restrict__ AOT)
{
    __shared__ float Vs[DD][256];
    __shared__ float at4[DD][DD];
    const int b  = blockIdx.y;
    const int n0 = blockIdx.x * 256;
    for (int i = threadIdx.x; i < DD * 256; i += 256) {
        int r = i >> 8, cc = i & 255;
        Vs[r][cc] = V[((size_t)b*DD + r)*NN + n0 + cc];
    }
    for (int i = threadIdx.x; i < DD * DD; i += 256)
        at4[i >> 5][i & 31] = attT[(size_t)b * (DD * DD) + i];
    __syncthreads();
    const int t = threadIdx.x;
    float acc[DD];
    #pragma unroll
    for (int d = 0; d < DD; ++d) acc[d] = 0.f;
    #pragma unroll 4
    for (int e = 0; e < DD; ++e) {
        float v = Vs[e][t];
        const float4* ar = (const float4*)at4[e];
        #pragma unroll
        for (int dq = 0; dq < 8; ++dq) {
            float4 a = ar[dq];
            acc[4*dq+0] += a.x * v; acc[4*dq+1] += a.y * v;
            acc[4*dq+2] += a.z * v; acc[4*dq+3] += a.w * v;
        }
    }
    const int n = n0 + t;
    const int h = n >> 7, w = n & 127;
    unsigned short* dst = AOT + (size_t)b*AOT_IMGE + (size_t)(h+1)*AOT_ROWE
                              + (size_t)(w+1)*AOT_CI;
    #pragma unroll
    for (int dq = 0; dq < 8; ++dq) {
        ushort4 u;
        u.x = f2bf(acc[4*dq+0]); u.y = f2bf(acc[4*dq+1]);
        u.z = f2bf(acc[4*dq+2]); u.w = f2bf(acc[4*dq+3]);
        *(ushort4*)(dst + 4*dq) = u;     // 8B stores, 8B-aligned (88B cells)
    }
}

// ---------------------------------------------------------------------------
// K4b: conv weight repack  wp fp32 [co][ci][3][3] -> Wt bf16 [kk][co][44ci]
// ---------------------------------------------------------------------------
__global__ __launch_bounds__(256) void wrepack_kernel(
    const float* __restrict__ wp, unsigned short* __restrict__ Wt)
{
    int i = blockIdx.x * 256 + threadIdx.x;
    if (i >= 9*256*32) return;
    int kk = i / (256*32);
    int r  = i % (256*32);
    int co = r >> 5, ci = r & 31;
    float v = wp[((size_t)co*32 + ci)*9 + kk];
    Wt[((size_t)kk*256 + co)*AOT_CI + ci] = f2bf(v);
}

// ---------------------------------------------------------------------------
// K5: conv implicit-GEMM, 2 H-rows per block (256n x 256co), 8 waves.
// grid (64, B) = 256 blocks = 1/CU.  Patch = 4 padded AOT rows staged linear;
// weights double-buffered per tap.  Frag reads = 2x ds_read_b64, conflict-free
// (88B pitch).  Epilogue: per-64co chunk LDS bounce -> float4 coalesced I/O.
// ---------------------------------------------------------------------------
__global__ __launch_bounds__(512, 1) void conv_kernel(
    const unsigned short* __restrict__ AOT, const unsigned short* __restrict__ Wt,
    const float* __restrict__ gammap, const float* __restrict__ x,
    float* __restrict__ out)
{
    __shared__ __align__(16) char lds[CONV_LDS];
    const int b   = blockIdx.y;
    const int h0  = blockIdx.x * 2;
    const int tid = threadIdx.x;
    const int wid = tid >> 6;
    const int lane = tid & 63;
    const int l15 = lane & 15;
    const int lj  = lane >> 4;
    const int wn  = wid & 1;        // which output row (n-half)
    const int wc  = wid >> 1;       // 64-co block

    // stage patch: padded rows h0..h0+3 (45,760 B linear)
    const char* psrc = (const char*)(AOT + (size_t)b*AOT_IMGE + (size_t)h0*AOT_ROWE);
    for (int i = tid; i < PATCH_SZ/16; i += 512)
        async_copy16(lds + i*16, psrc + i*16);
    // stage weights tap 0
    for (int i = tid; i < WSLAB/16; i += 512)
        async_copy16(lds + PATCH_SZ + i*16, (const char*)Wt + i*16);
    __syncthreads();

    f32x4 acc[4][8];
    #pragma unroll
    for (int cf = 0; cf < 4; ++cf)
        #pragma unroll
        for (int nf = 0; nf < 8; ++nf)
            acc[cf][nf] = (f32x4){0.f, 0.f, 0.f, 0.f};

    for (int kk = 0; kk < 9; ++kk) {
        if (kk < 8) {                       // prefetch next tap's weights
            const char* wsrc = (const char*)Wt + (size_t)(kk+1)*WSLAB;
            char* wdst = lds + PATCH_SZ + ((kk+1)&1)*WSLAB;
            for (int i = tid; i < WSLAB/16; i += 512)
                async_copy16(wdst + i*16, wsrc + i*16);
        }
        const int kh = kk / 3, kw = kk % 3;
        const char* wbase = lds + PATCH_SZ + (kk&1)*WSLAB;
        bf16x8 af[4];
        #pragma unroll
        for (int cf = 0; cf < 4; ++cf)
            af[cf] = ld_frag8(wbase + (wc*64 + cf*16 + l15)*88 + lj*16);
        #pragma unroll
        for (int nf = 0; nf < 8; ++nf) {
            const int cell = (wn + kh)*130 + nf*16 + l15 + kw;
            const bf16x8 bfr = ld_frag8(lds + cell*88 + lj*16);
            #pragma unroll
            for (int cf = 0; cf < 4; ++cf)
                acc[cf][nf] = __builtin_amdgcn_mfma_f32_16x16x32_bf16(
                    af[cf], bfr, acc[cf][nf], 0, 0, 0);
        }
        __syncthreads();
    }

    // ---- epilogue: 4 chunks of 64 co; LDS bounce -> coalesced float4 I/O ----
    const float g0 = gammap[0];
    float* lf = (float*)lds;
    for (int k = 0; k < 4; ++k) {
        if (wc == k) {
            #pragma unroll
            for (int cf = 0; cf < 4; ++cf) {
                const int rl = cf*16 + 4*lj;
                #pragma unroll
                for (int nf = 0; nf < 8; ++nf) {
                    const int col = wn*128 + nf*16 + l15;
                    #pragma unroll
                    for (int j = 0; j < 4; ++j)
                        lf[(rl + j)*EPI_PITCH + col] = acc[cf][nf][j];
                }
            }
        }
        __syncthreads();
        #pragma unroll
        for (int it = 0; it < 8; ++it) {
            const int idx = tid + it*512;           // 0..4095
            const int row = idx >> 6, c4 = idx & 63;
            const int co  = k*64 + row;
            const size_t g = ((size_t)b*CC + co)*NN + (size_t)h0*WW + c4*4;
            float4 v  = *(const float4*)(lf + row*EPI_PITCH + c4*4);
            float4 xv = *(const float4*)(x + g);
            float4 o;
            o.x = g0*gelu_fast(v.x) + xv.x;
            o.y = g0*gelu_fast(v.y) + xv.y;
            o.z = g0*gelu_fast(v.z) + xv.z;
            o.w = g0*gelu_fast(v.w) + xv.w;
            *(float4*)(out + g) = o;
        }
        __syncthreads();
    }
}

// ---------------------------------------------------------------------------
extern "C" void kernel_launch(void* const* d_in, const int* in_sizes, int n_in,
                              void* d_out, int out_size, void* d_ws, size_t ws_size,
                              hipStream_t stream)
{
    const float* x  = (const float*)d_in[0];
    const float* wq = (const float*)d_in[1];
    const float* bq = (const float*)d_in[2];
    const float* wk = (const float*)d_in[3];
    const float* bk = (const float*)d_in[4];
    const float* wv = (const float*)d_in[5];
    const float* bv = (const float*)d_in[6];
    const float* wp = (const float*)d_in[7];
    const float* gm = (const float*)d_in[8];
    float* out = (float*)d_out;

    // V scratch aliased into d_out (pv reads it before conv overwrites out).
    float* Vbuf = out;

    char* ws = (char*)d_ws;
    unsigned short* AOT   = (unsigned short*)ws;
    unsigned short* Wt    = (unsigned short*)(ws + AOT_ALLOC);
    unsigned short* Apack = (unsigned short*)(ws + AOT_ALLOC + WT_BYTES);
    float* Ep  = (float*)(ws + AOT_ALLOC + WT_BYTES + APACK_BYTES);
    float* ATT = Ep + 64*BB*1024;

    hipMemsetAsync(AOT, 0, AOT_ALLOC, stream);   // zero spatial borders
    wrepack_kernel <<<dim3(288), 256, 0, stream>>>(wp, Wt);
    wrepack2_kernel<<<dim3((4*96*68 + 255)/256), 256, 0, stream>>>(wq, wk, wv, Apack);
    qkv_mfma_kernel<<<dim3(64, BB), 512, 0, stream>>>(x, Apack, bq, bk, bv, Vbuf, Ep);
    softmax_kernel <<<dim3(BB), dim3(32, 32), 0, stream>>>(Ep, ATT);
    pv_kernel      <<<dim3(NN/256, BB), 256, 0, stream>>>(Vbuf, ATT, AOT);
    conv_kernel    <<<dim3(64, BB), 512, 0, stream>>>(AOT, Wt, gm, x, out);
}

// Round 6
// 84.394 us; speedup vs baseline: 9.9278x; 1.1055x over previous
//
#include <hip/hip_runtime.h>
#include <hip/hip_bf16.h>
#include <math.h>

#define BB 4
#define CC 256
#define HH 128
#define WW 128
#define NN (HH*WW)
#define DD 32

// AOT: attention output, bf16, spatially padded +1 border, ci padded 32->44.
#define AOT_CI   44
#define AOT_ROWE (130*AOT_CI)                  // shorts per padded row (5720)
#define AOT_IMGE (130*AOT_ROWE)                // shorts per batch (743600)
#define AOT_BYTES ((size_t)BB*AOT_IMGE*2)      // 5,948,800
#define AOT_ALLOC (AOT_BYTES + 1024)           // 5,949,824 (16-aligned)

#define WT_BYTES (9*256*AOT_CI*2)              // 202,752

// conv LDS geometry
#define PATCH_SZ 45760                         // 4 padded rows * 130 * 88
#define WSLAB    22528                         // 256 co * 88
#define CONV_LDS (PATCH_SZ + 2*WSLAB)          // 90,816
#define EPI_PITCH 260

// qkv geometry: A pre-swizzled to MFMA fragment order [32 kstep][3 cf][64 lane][8 bf16]
#define ASWZ_BYTES 98304
#define QKP 260

typedef __attribute__((ext_vector_type(8)))  short bf16x8;
typedef __attribute__((ext_vector_type(4)))  float f32x4;
typedef __attribute__((ext_vector_type(16))) float f32x16;

__device__ inline void async_copy16(void* lds, const void* g) {
    __builtin_amdgcn_global_load_lds(
        (const __attribute__((address_space(1))) unsigned int*)g,
        (__attribute__((address_space(3))) unsigned int*)lds, 16, 0, 0);
}

__device__ inline unsigned short f2bf(float f) {
    __hip_bfloat16 h = __float2bfloat16(f);
    return *reinterpret_cast<unsigned short*>(&h);
}

__device__ inline void split2(float v, unsigned short& h, unsigned short& l) {
    __hip_bfloat16 hb = __float2bfloat16(v);
    float r = v - __bfloat162float(hb);     // exact (Sterbenz)
    __hip_bfloat16 lb = __float2bfloat16(r);
    h = *reinterpret_cast<unsigned short*>(&hb);
    l = *reinterpret_cast<unsigned short*>(&lb);
}

// 8B+8B LDS load of a bf16x8 fragment (88B row pitch is only 8B-aligned)
__device__ inline bf16x8 ld_frag8(const char* p) {
    union { bf16x8 v; short4 h[2]; } u;
    u.h[0] = *(const short4*)(p);
    u.h[1] = *(const short4*)(p + 8);
    return u.v;
}

// A&S 7.1.26 erf approximation, |err| ~1e-6
__device__ inline float gelu_fast(float v) {
    float a = fabsf(v) * 0.70710678118654752f;
    float t = __fdividef(1.0f, fmaf(0.3275911f, a, 1.0f));
    float p = t * fmaf(t, fmaf(t, fmaf(t, fmaf(t, 1.061405429f, -1.453152027f),
                                       1.421413741f), -0.284496736f), 0.254829592f);
    float e = 1.0f - p * __expf(-a * a);
    float erfv = (v < 0.0f) ? -e : e;
    return 0.5f * v * (1.0f + erfv);
}

// ---------------------------------------------------------------------------
// K0z: fast zero (replaces hipMemsetAsync's 40us rocclr fill).
// ---------------------------------------------------------------------------
__global__ __launch_bounds__(256) void zero_kernel(uint4* __restrict__ p, int n16)
{
    for (int i = blockIdx.x*256 + threadIdx.x; i < n16; i += gridDim.x*256)
        p[i] = (uint4){0u, 0u, 0u, 0u};
}

// ---------------------------------------------------------------------------
// K0a: pack W rows (q:0-31, k:32-63, v:64-95) into split-bf16 A image in
// MFMA fragment order: Aswz[((s*3+cf)*64 + lane)*8 + j]
//   row = cf*32 + (lane&31); k = s*16 + (lane>>5)*8 + j; c = k>>1;
//   slot even -> w_hi, odd -> w_lo.
// ---------------------------------------------------------------------------
__global__ __launch_bounds__(256) void wrepack2_kernel(
    const float* __restrict__ wq, const float* __restrict__ wk,
    const float* __restrict__ wv, unsigned short* __restrict__ Aswz)
{
    int i = blockIdx.x*256 + threadIdx.x;        // 32*3*64*8 = 49152
    if (i >= 49152) return;
    int j    = i & 7;
    int lane = (i >> 3) & 63;
    int cf   = (i >> 9) % 3;
    int s    = i / 1536;
    int row  = cf*32 + (lane & 31);
    int k    = s*16 + (lane >> 5)*8 + j;
    int c    = k >> 1;
    float w  = (row < 32) ? wq[row*256 + c]
             : (row < 64) ? wk[(row-32)*256 + c]
                          : wv[(row-64)*256 + c];
    unsigned short h, l;
    split2(w, h, l);
    Aswz[i] = (k & 1) ? l : h;
}

// ---------------------------------------------------------------------------
// K1: QKV streaming MFMA GEMM (barrier-free K-loop) + fused energy partial.
// grid (64, B), 512 thr = 8 waves; wave w owns n-cols [32w, 32w+32).
// A (96 KB, fragment-ordered) staged once via global_load_lds; x loaded
// straight to registers (4-step prefetch queue), split to (hi,lo) in-reg,
// MFMA 32x32x16: acc[cf] += A[cf] * {x_hi dup}  then  * {x_lo dup}.
// Epilogue: Q,K (+bias) -> LDS (reuse A region), V (+bias) -> global,
// then 32x32 energy partial over this block's 256 n.
// ---------------------------------------------------------------------------
__global__ __launch_bounds__(512, 1) void qkv_mfma_kernel(
    const float* __restrict__ x, const unsigned short* __restrict__ Aswz,
    const float* __restrict__ bq, const float* __restrict__ bk,
    const float* __restrict__ bv,
    float* __restrict__ Vout, float* __restrict__ Ep)
{
    __shared__ __align__(16) char lds[ASWZ_BYTES];   // A region, reused for QK
    __shared__ float biasL[96];
    const int b    = blockIdx.y;
    const int s    = blockIdx.x;
    const int n0   = s * 256;
    const int tid  = threadIdx.x;
    const int lane = tid & 63;
    const int wid  = tid >> 6;
    const int l31  = lane & 31;
    const int lh   = lane >> 5;
    const int nloc = 32*wid + l31;               // block-local n (0..255)

    // stage A: 6144 x 16B, linear
    for (int i = tid; i < 6144; i += 512)
        async_copy16(lds + i*16, (const char*)Aswz + i*16);
    if (tid < 96)
        biasL[tid] = (tid < 32) ? bq[tid] : (tid < 64) ? bk[tid-32] : bv[tid-64];

    // per-lane x base: channels 4*lh + j, column n0 + nloc
    const float* xlane = x + ((size_t)b*CC + 4*lh)*NN + (n0 + nloc);

    f32x16 acc0 = {0}, acc1 = {0}, acc2 = {0};

    // prefetch queue: steps 0..3
    float xq[4][4];
    #pragma unroll
    for (int p0 = 0; p0 < 4; ++p0) {
        const float* p = xlane + (size_t)(8*p0)*NN;
        xq[p0][0] = p[0];            xq[p0][1] = p[(size_t)NN];
        xq[p0][2] = p[(size_t)2*NN]; xq[p0][3] = p[(size_t)3*NN];
    }

    __syncthreads();                              // A resident (drains vmcnt)

    for (int su = 0; su < 32; su += 4) {
        #pragma unroll
        for (int ph = 0; ph < 4; ++ph) {
            const int st = su + ph;
            // A fragments for this k-step (stride-1, conflict-free)
            const char* ab = lds + (size_t)(st*3)*1024 + lane*16;
            bf16x8 a0 = *(const bf16x8*)(ab);
            bf16x8 a1 = *(const bf16x8*)(ab + 1024);
            bf16x8 a2 = *(const bf16x8*)(ab + 2048);
            // consume queue slot
            float xv0 = xq[ph][0], xv1 = xq[ph][1];
            float xv2 = xq[ph][2], xv3 = xq[ph][3];
            // prefetch step st+4 into same slot
            if (st + 4 < 32) {
                const float* p = xlane + (size_t)(8*(st+4))*NN;
                xq[ph][0] = p[0];            xq[ph][1] = p[(size_t)NN];
                xq[ph][2] = p[(size_t)2*NN]; xq[ph][3] = p[(size_t)3*NN];
            }
            // split to hi/lo duplicated-slot fragments
            union { bf16x8 v; unsigned short u[8]; } B1, B2;
            unsigned short h, l;
            split2(xv0, h, l); B1.u[0] = h; B1.u[1] = h; B2.u[0] = l; B2.u[1] = l;
            split2(xv1, h, l); B1.u[2] = h; B1.u[3] = h; B2.u[2] = l; B2.u[3] = l;
            split2(xv2, h, l); B1.u[4] = h; B1.u[5] = h; B2.u[4] = l; B2.u[5] = l;
            split2(xv3, h, l); B1.u[6] = h; B1.u[7] = h; B2.u[6] = l; B2.u[7] = l;

            acc0 = __builtin_amdgcn_mfma_f32_32x32x16_bf16(a0, B1.v, acc0, 0, 0, 0);
            acc1 = __builtin_amdgcn_mfma_f32_32x32x16_bf16(a1, B1.v, acc1, 0, 0, 0);
            acc2 = __builtin_amdgcn_mfma_f32_32x32x16_bf16(a2, B1.v, acc2, 0, 0, 0);
            acc0 = __builtin_amdgcn_mfma_f32_32x32x16_bf16(a0, B2.v, acc0, 0, 0, 0);
            acc1 = __builtin_amdgcn_mfma_f32_32x32x16_bf16(a1, B2.v, acc1, 0, 0, 0);
            acc2 = __builtin_amdgcn_mfma_f32_32x32x16_bf16(a2, B2.v, acc2, 0, 0, 0);
        }
    }

    __syncthreads();                 // all waves done reading A; reuse as QK
    float* qk = (float*)lds;         // [64 rows][QKP]
    #pragma unroll
    for (int r = 0; r < 16; ++r) {
        const int rsub = (r & 3) + 8*(r >> 2) + 4*lh;   // 0..31
        {   // cf=0 -> Q rows 0..31
            const int row = rsub;
            qk[row*QKP + nloc] = acc0[r] + biasL[row];
        }
        {   // cf=1 -> K rows 32..63
            const int row = 32 + rsub;
            qk[row*QKP + nloc] = acc1[r] + biasL[row];
        }
        {   // cf=2 -> V rows 64..95
            const int row = 64 + rsub;
            Vout[((size_t)b*DD + rsub)*NN + n0 + nloc] = acc2[r] + biasL[row];
        }
    }
    __syncthreads();

    // energy partial: E[d][e] = sum_n Q[d][n]*K[e][n] over 256 n
    const int d  = tid >> 4;
    const int e0 = tid & 15;
    const float* qrow = qk + d*QKP;
    const float* ka   = qk + (32 + e0)*QKP;
    const float* kb   = qk + (48 + e0)*QKP;
    float s0 = 0.f, s1 = 0.f;
    for (int n4 = 0; n4 < 256; n4 += 4) {
        float4 qv = *(const float4*)(qrow + n4);
        float4 va = *(const float4*)(ka + n4);
        float4 vb = *(const float4*)(kb + n4);
        s0 += qv.x*va.x + qv.y*va.y + qv.z*va.z + qv.w*va.w;
        s1 += qv.x*vb.x + qv.y*vb.y + qv.z*vb.z + qv.w*vb.w;
    }
    float* ep = Ep + ((size_t)s*BB + b)*1024;
    ep[d*32 + e0]      = s0;
    ep[d*32 + e0 + 16] = s1;
}

// ---------------------------------------------------------------------------
// K3: softmax over reduced partials.  softmax(max-E)==softmax(-E).
// ---------------------------------------------------------------------------
__global__ __launch_bounds__(1024) void softmax_kernel(
    const float* __restrict__ Ep, float* __restrict__ attT)
{
    const int b = blockIdx.x;
    const int e = threadIdx.x, d = threadIdx.y;
    float s = 0.f;
    for (int p = 0; p < 64; ++p)
        s += Ep[((size_t)p * BB + b) * (DD * DD) + d * DD + e];
    float nv = -s;
    float m = nv;
    for (int off = 16; off > 0; off >>= 1) m = fmaxf(m, __shfl_xor(m, off, 32));
    float pe = expf(nv - m);
    float su = pe;
    for (int off = 16; off > 0; off >>= 1) su += __shfl_xor(su, off, 32);
    attT[(size_t)b * (DD * DD) + e * DD + d] = pe / su;
}

// ---------------------------------------------------------------------------
// K4: PV — writes bf16 AOT padded layout (ci pitch 44).
// ---------------------------------------------------------------------------
__global__ __launch_bounds__(256) void pv_kernel(
    const float* __restrict__ V, const float* __restrict__ attT,
    unsigned short* __restrict__ AOT)
{
    __shared__ float Vs[DD][256];
    __shared__ float at4[DD][DD];
    const int b  = blockIdx.y;
    const int n0 = blockIdx.x * 256;
    for (int i = threadIdx.x; i < DD * 256; i += 256) {
        int r = i >> 8, cc = i & 255;
        Vs[r][cc] = V[((size_t)b*DD + r)*NN + n0 + cc];
    }
    for (int i = threadIdx.x; i < DD * DD; i += 256)
        at4[i >> 5][i & 31] = attT[(size_t)b * (DD * DD) + i];
    __syncthreads();
    const int t = threadIdx.x;
    float acc[DD];
    #pragma unroll
    for (int d = 0; d < DD; ++d) acc[d] = 0.f;
    #pragma unroll 4
    for (int e = 0; e < DD; ++e) {
        float v = Vs[e][t];
        const float4* ar = (const float4*)at4[e];
        #pragma unroll
        for (int dq = 0; dq < 8; ++dq) {
            float4 a = ar[dq];
            acc[4*dq+0] += a.x * v; acc[4*dq+1] += a.y * v;
            acc[4*dq+2] += a.z * v; acc[4*dq+3] += a.w * v;
        }
    }
    const int n = n0 + t;
    const int h = n >> 7, w = n & 127;
    unsigned short* dst = AOT + (size_t)b*AOT_IMGE + (size_t)(h+1)*AOT_ROWE
                              + (size_t)(w+1)*AOT_CI;
    #pragma unroll
    for (int dq = 0; dq < 8; ++dq) {
        ushort4 u;
        u.x = f2bf(acc[4*dq+0]); u.y = f2bf(acc[4*dq+1]);
        u.z = f2bf(acc[4*dq+2]); u.w = f2bf(acc[4*dq+3]);
        *(ushort4*)(dst + 4*dq) = u;
    }
}

// ---------------------------------------------------------------------------
// K4b: conv weight repack  wp fp32 [co][ci][3][3] -> Wt bf16 [kk][co][44ci]
// ---------------------------------------------------------------------------
__global__ __launch_bounds__(256) void wrepack_kernel(
    const float* __restrict__ wp, unsigned short* __restrict__ Wt)
{
    int i = blockIdx.x * 256 + threadIdx.x;
    if (i >= 9*256*32) return;
    int kk = i / (256*32);
    int r  = i % (256*32);
    int co = r >> 5, ci = r & 31;
    float v = wp[((size_t)co*32 + ci)*9 + kk];
    Wt[((size_t)kk*256 + co)*AOT_CI + ci] = f2bf(v);
}

// ---------------------------------------------------------------------------
// K5: conv implicit-GEMM, 2 H-rows per block (256n x 256co), 8 waves.
// ---------------------------------------------------------------------------
__global__ __launch_bounds__(512, 1) void conv_kernel(
    const unsigned short* __restrict__ AOT, const unsigned short* __restrict__ Wt,
    const float* __restrict__ gammap, const float* __restrict__ x,
    float* __restrict__ out)
{
    __shared__ __align__(16) char lds[CONV_LDS];
    const int b   = blockIdx.y;
    const int h0  = blockIdx.x * 2;
    const int tid = threadIdx.x;
    const int wid = tid >> 6;
    const int lane = tid & 63;
    const int l15 = lane & 15;
    const int lj  = lane >> 4;
    const int wn  = wid & 1;        // which output row (n-half)
    const int wc  = wid >> 1;       // 64-co block

    const char* psrc = (const char*)(AOT + (size_t)b*AOT_IMGE + (size_t)h0*AOT_ROWE);
    for (int i = tid; i < PATCH_SZ/16; i += 512)
        async_copy16(lds + i*16, psrc + i*16);
    for (int i = tid; i < WSLAB/16; i += 512)
        async_copy16(lds + PATCH_SZ + i*16, (const char*)Wt + i*16);
    __syncthreads();

    f32x4 acc[4][8];
    #pragma unroll
    for (int cf = 0; cf < 4; ++cf)
        #pragma unroll
        for (int nf = 0; nf < 8; ++nf)
            acc[cf][nf] = (f32x4){0.f, 0.f, 0.f, 0.f};

    for (int kk = 0; kk < 9; ++kk) {
        if (kk < 8) {
            const char* wsrc = (const char*)Wt + (size_t)(kk+1)*WSLAB;
            char* wdst = lds + PATCH_SZ + ((kk+1)&1)*WSLAB;
            for (int i = tid; i < WSLAB/16; i += 512)
                async_copy16(wdst + i*16, wsrc + i*16);
        }
        const int kh = kk / 3, kw = kk % 3;
        const char* wbase = lds + PATCH_SZ + (kk&1)*WSLAB;
        bf16x8 af[4];
        #pragma unroll
        for (int cf = 0; cf < 4; ++cf)
            af[cf] = ld_frag8(wbase + (wc*64 + cf*16 + l15)*88 + lj*16);
        #pragma unroll
        for (int nf = 0; nf < 8; ++nf) {
            const int cell = (wn + kh)*130 + nf*16 + l15 + kw;
            const bf16x8 bfr = ld_frag8(lds + cell*88 + lj*16);
            #pragma unroll
            for (int cf = 0; cf < 4; ++cf)
                acc[cf][nf] = __builtin_amdgcn_mfma_f32_16x16x32_bf16(
                    af[cf], bfr, acc[cf][nf], 0, 0, 0);
        }
        __syncthreads();
    }

    // epilogue: 4 chunks of 64 co; LDS bounce -> coalesced float4 I/O
    const float g0 = gammap[0];
    float* lf = (float*)lds;
    for (int k = 0; k < 4; ++k) {
        if (wc == k) {
            #pragma unroll
            for (int cf = 0; cf < 4; ++cf) {
                const int rl = cf*16 + 4*lj;
                #pragma unroll
                for (int nf = 0; nf < 8; ++nf) {
                    const int col = wn*128 + nf*16 + l15;
                    #pragma unroll
                    for (int j = 0; j < 4; ++j)
                        lf[(rl + j)*EPI_PITCH + col] = acc[cf][nf][j];
                }
            }
        }
        __syncthreads();
        #pragma unroll
        for (int it = 0; it < 8; ++it) {
            const int idx = tid + it*512;
            const int row = idx >> 6, c4 = idx & 63;
            const int co  = k*64 + row;
            const size_t g = ((size_t)b*CC + co)*NN + (size_t)h0*WW + c4*4;
            float4 v  = *(const float4*)(lf + row*EPI_PITCH + c4*4);
            float4 xv = *(const float4*)(x + g);
            float4 o;
            o.x = g0*gelu_fast(v.x) + xv.x;
            o.y = g0*gelu_fast(v.y) + xv.y;
            o.z = g0*gelu_fast(v.z) + xv.z;
            o.w = g0*gelu_fast(v.w) + xv.w;
            *(float4*)(out + g) = o;
        }
        __syncthreads();
    }
}

// ---------------------------------------------------------------------------
extern "C" void kernel_launch(void* const* d_in, const int* in_sizes, int n_in,
                              void* d_out, int out_size, void* d_ws, size_t ws_size,
                              hipStream_t stream)
{
    const float* x  = (const float*)d_in[0];
    const float* wq = (const float*)d_in[1];
    const float* bq = (const float*)d_in[2];
    const float* wk = (const float*)d_in[3];
    const float* bk = (const float*)d_in[4];
    const float* wv = (const float*)d_in[5];
    const float* bv = (const float*)d_in[6];
    const float* wp = (const float*)d_in[7];
    const float* gm = (const float*)d_in[8];
    float* out = (float*)d_out;

    // V scratch aliased into d_out (pv reads it before conv overwrites out).
    float* Vbuf = out;

    char* ws = (char*)d_ws;
    unsigned short* AOT  = (unsigned short*)ws;
    unsigned short* Wt   = (unsigned short*)(ws + AOT_ALLOC);
    unsigned short* Aswz = (unsigned short*)(ws + AOT_ALLOC + WT_BYTES);
    float* Ep  = (float*)(ws + AOT_ALLOC + WT_BYTES + ASWZ_BYTES);
    float* ATT = Ep + 64*BB*1024;

    zero_kernel    <<<dim3(1024), 256, 0, stream>>>((uint4*)AOT, (int)(AOT_ALLOC/16));
    wrepack_kernel <<<dim3(288), 256, 0, stream>>>(wp, Wt);
    wrepack2_kernel<<<dim3(192), 256, 0, stream>>>(wq, wk, wv, Aswz);
    qkv_mfma_kernel<<<dim3(64, BB), 512, 0, stream>>>(x, Aswz, bq, bk, bv, Vbuf, Ep);
    softmax_kernel <<<dim3(BB), dim3(32, 32), 0, stream>>>(Ep, ATT);
    pv_kernel      <<<dim3(NN/256, BB), 256, 0, stream>>>(Vbuf, ATT, AOT);
    conv_kernel    <<<dim3(64, BB), 512, 0, stream>>>(AOT, Wt, gm, x, out);
}